// Round 1
// baseline (927.936 us; speedup 1.0000x reference)
//
#include <hip/hip_runtime.h>
#include <math.h>

#define U_CNT 100000
#define N_CNT 50000
#define C_CNT 20
#define D_DIM 128
#define E_CNT 1000000
#define K_CNT 50000
#define NS_CNT 9
#define CAP 64

// ---------------- workspace layout (bytes) ----------------
// cnt    : U * 4                  @ 0          (400000)
// Wt     : 256*512*4 = 524288     @ 400384
// bucket : U*CAP*4 = 25,600,000   @ 924672
// xh     : U*128*4 = 51,200,000   @ 26,524,672   (x, then h in-place)
// total ~77.7 MB
#define OFF_CNT    0
#define OFF_WT     400384
#define OFF_BUCKET 924672
#define OFF_XH     26524672

__global__ void k_zero(int* __restrict__ cnt) {
    int i = blockIdx.x * 256 + threadIdx.x;
    if (i < U_CNT) cnt[i] = 0;
}

// Wt[k][j]: k<128 -> W_ih[j][k], k>=128 -> W_hh[j][k-128]   (Wt is [256][512])
__global__ void k_wt(const float* __restrict__ Wih, const float* __restrict__ Whh,
                     float* __restrict__ Wt) {
    int idx = blockIdx.x * 256 + threadIdx.x;   // 131072 total
    if (idx >= 256 * 512) return;
    int k = idx >> 9, j = idx & 511;
    float v = (k < 128) ? Wih[j * 128 + k] : Whh[j * 128 + (k - 128)];
    Wt[k * 512 + j] = v;
}

__global__ void k_bucket(const int* __restrict__ dst, int* __restrict__ cnt,
                         int* __restrict__ bucket) {
    int e = blockIdx.x * 256 + threadIdx.x;
    if (e >= E_CNT) return;
    int d = dst[e];
    int slot = atomicAdd(&cnt[d], 1);
    if (slot < CAP) bucket[d * CAP + slot] = e;
}

// one wave (64 lanes) per user; lane l holds dims {2l, 2l+1} as float2
__global__ void k_agg(const float* __restrict__ user_emb, const float* __restrict__ news_emb,
                      const float* __restrict__ cat_emb, const int* __restrict__ esrc,
                      const int* __restrict__ ecat, const int* __restrict__ cnt,
                      const int* __restrict__ bucket, float* __restrict__ xh) {
    int wid  = (blockIdx.x * blockDim.x + threadIdx.x) >> 6;
    int lane = threadIdx.x & 63;
    if (wid >= U_CNT) return;
    int deg = cnt[wid];
    if (deg > CAP) deg = CAP;
    const float2* news2 = (const float2*)news_emb;
    const float2* cat2  = (const float2*)cat_emb;
    float2 acc = {0.f, 0.f};
    for (int t = 0; t < deg; ++t) {
        int e = bucket[wid * CAP + t];
        int s = esrc[e];
        int c = ecat[e];
        float2 nv = news2[(size_t)s * 64 + lane];
        float2 cv = cat2[c * 64 + lane];
        acc.x += nv.x * cv.x;
        acc.y += nv.y * cv.y;
    }
    float inv = 1.0f / (float)(deg < 1 ? 1 : deg);
    float2 ue = ((const float2*)user_emb)[(size_t)wid * 64 + lane];
    float2 xv = {ue.x + acc.x * inv, ue.y + acc.y * inv};
    ((float2*)xh)[(size_t)wid * 64 + lane] = xv;
}

// gates[U,512] = [x | user_emb] @ Wt  (+biases), fused LSTM epilogue, h in-place into xh.
// BM=32 users/block, BN=512 (all gates), BK=32, 256 threads.
// thread (tx,ty): rows ty*4..ty*4+3, cols {s*128 + tx*4 .. +3} for s=0..3  -> all 4 gates
// for (user,dim) in-register.
__global__ __launch_bounds__(256) void k_gemm_lstm(
    const float* __restrict__ xin,       // x rows (xh buffer)
    const float* __restrict__ user_emb,
    const float* __restrict__ Wt,        // [256][512]
    const float* __restrict__ b_ih, const float* __restrict__ b_hh,
    const float* __restrict__ cx,
    float* __restrict__ hout)            // == xh buffer (in-place)
{
    __shared__ float As[32][32];     // [kk][m]
    __shared__ float Bs[32][512];    // [kk][j]
    int t  = threadIdx.x;
    int tx = t & 31, ty = t >> 5;
    int u0 = blockIdx.x * 32;

    float acc[4][4][4];  // [m][s][i]
#pragma unroll
    for (int m = 0; m < 4; ++m)
#pragma unroll
        for (int s = 0; s < 4; ++s)
#pragma unroll
            for (int i = 0; i < 4; ++i) acc[m][s][i] = 0.f;

    for (int kstep = 0; kstep < 8; ++kstep) {
        int k0 = kstep * 32;
        // stage A (transposed): thread t loads 4 k-consecutive floats of one user row
        {
            int ul = t >> 3;   // 0..31 local user
            int kg = t & 7;    // 0..7 -> k-group of 4
            const float* src = (k0 < 128) ? xin : user_emb;
            int koff = (k0 & 127) + kg * 4;
            float4 v = *(const float4*)&src[(size_t)(u0 + ul) * 128 + koff];
            As[kg * 4 + 0][ul] = v.x;
            As[kg * 4 + 1][ul] = v.y;
            As[kg * 4 + 2][ul] = v.z;
            As[kg * 4 + 3][ul] = v.w;
        }
        // stage B: rows k0..k0+31, 512 cols, fully coalesced float4
        {
#pragma unroll
            for (int i = 0; i < 16; ++i) {
                int idx = t + 256 * i;     // float4 index, 0..4095
                int row = idx >> 7;
                int c4  = idx & 127;
                *(float4*)&Bs[row][c4 * 4] =
                    *(const float4*)&Wt[(size_t)(k0 + row) * 512 + c4 * 4];
            }
        }
        __syncthreads();
#pragma unroll
        for (int kk = 0; kk < 32; ++kk) {
            float4 av = *(const float4*)&As[kk][ty * 4];
            float a[4] = {av.x, av.y, av.z, av.w};
            float4 b[4];
#pragma unroll
            for (int s = 0; s < 4; ++s) b[s] = *(const float4*)&Bs[kk][s * 128 + tx * 4];
#pragma unroll
            for (int m = 0; m < 4; ++m)
#pragma unroll
                for (int s = 0; s < 4; ++s) {
                    acc[m][s][0] += a[m] * b[s].x;
                    acc[m][s][1] += a[m] * b[s].y;
                    acc[m][s][2] += a[m] * b[s].z;
                    acc[m][s][3] += a[m] * b[s].w;
                }
        }
        __syncthreads();
    }

    // epilogue: biases + LSTM cell, write h in-place
    float bsum[4][4];
#pragma unroll
    for (int s = 0; s < 4; ++s) {
        float4 v1 = *(const float4*)&b_ih[s * 128 + tx * 4];
        float4 v2 = *(const float4*)&b_hh[s * 128 + tx * 4];
        bsum[s][0] = v1.x + v2.x;
        bsum[s][1] = v1.y + v2.y;
        bsum[s][2] = v1.z + v2.z;
        bsum[s][3] = v1.w + v2.w;
    }
#pragma unroll
    for (int m = 0; m < 4; ++m) {
        int u = u0 + ty * 4 + m;
        float4 cxv = *(const float4*)&cx[(size_t)u * 128 + tx * 4];
        float cvals[4] = {cxv.x, cxv.y, cxv.z, cxv.w};
        float hvals[4];
#pragma unroll
        for (int i = 0; i < 4; ++i) {
            float I = acc[m][0][i] + bsum[0][i];
            float F = acc[m][1][i] + bsum[1][i];
            float G = acc[m][2][i] + bsum[2][i];
            float O = acc[m][3][i] + bsum[3][i];
            float si = 1.f / (1.f + expf(-I));
            float sf = 1.f / (1.f + expf(-F));
            float so = 1.f / (1.f + expf(-O));
            float cn = sf * cvals[i] + si * tanhf(G);
            hvals[i] = so * tanhf(cn);
        }
        float4 hv4 = {hvals[0], hvals[1], hvals[2], hvals[3]};
        *(float4*)&hout[(size_t)u * 128 + tx * 4] = hv4;
    }
}

// one wave per k; lane l holds dims {2l,2l+1}; butterfly-reduce each of 9 dots
__global__ void k_score(const float* __restrict__ h, const float* __restrict__ news_emb,
                        const int* __restrict__ ns_idx, const int* __restrict__ usi,
                        float* __restrict__ out) {
    int wid  = (blockIdx.x * blockDim.x + threadIdx.x) >> 6;
    int lane = threadIdx.x & 63;
    if (wid >= K_CNT) return;
    int u = usi[wid];
    float2 hv = ((const float2*)h)[(size_t)u * 64 + lane];
    const float2* n2 = (const float2*)news_emb;
    float val = 0.f;
#pragma unroll
    for (int j = 0; j < 9; ++j) {
        int n = ns_idx[wid * 9 + j];
        float2 nv = n2[(size_t)n * 64 + lane];
        float p = hv.x * nv.x + hv.y * nv.y;
#pragma unroll
        for (int off = 32; off; off >>= 1) p += __shfl_xor(p, off, 64);
        if (lane == j) val = p;
    }
    if (lane < 9) out[wid * 9 + lane] = val;
}

extern "C" void kernel_launch(void* const* d_in, const int* in_sizes, int n_in,
                              void* d_out, int out_size, void* d_ws, size_t ws_size,
                              hipStream_t stream) {
    const float* user_emb = (const float*)d_in[0];
    const float* news_emb = (const float*)d_in[1];
    const float* cat_emb  = (const float*)d_in[2];
    const float* cx       = (const float*)d_in[3];
    const float* W_ih     = (const float*)d_in[4];
    const float* W_hh     = (const float*)d_in[5];
    const float* b_ih     = (const float*)d_in[6];
    const float* b_hh     = (const float*)d_in[7];
    const int* edge_src   = (const int*)d_in[8];
    const int* edge_dst   = (const int*)d_in[9];
    const int* edge_cat   = (const int*)d_in[10];
    const int* ns_idx     = (const int*)d_in[11];
    const int* usi        = (const int*)d_in[12];
    float* out = (float*)d_out;

    char* ws = (char*)d_ws;
    int*   cnt    = (int*)(ws + OFF_CNT);
    float* Wt     = (float*)(ws + OFF_WT);
    int*   bucket = (int*)(ws + OFF_BUCKET);
    float* xh     = (float*)(ws + OFF_XH);

    k_zero<<<(U_CNT + 255) / 256, 256, 0, stream>>>(cnt);
    k_wt<<<512, 256, 0, stream>>>(W_ih, W_hh, Wt);
    k_bucket<<<(E_CNT + 255) / 256, 256, 0, stream>>>(edge_dst, cnt, bucket);
    k_agg<<<25000, 256, 0, stream>>>(user_emb, news_emb, cat_emb, edge_src, edge_cat,
                                     cnt, bucket, xh);
    k_gemm_lstm<<<3125, 256, 0, stream>>>(xh, user_emb, Wt, b_ih, b_hh, cx, xh);
    k_score<<<(K_CNT * 64 + 255) / 256, 256, 0, stream>>>(xh, news_emb, ns_idx, usi, out);
}

// Round 2
// 797.295 us; speedup vs baseline: 1.1639x; 1.1639x over previous
//
#include <hip/hip_runtime.h>
#include <math.h>

#define U_CNT 100000
#define N_CNT 50000
#define C_CNT 20
#define D_DIM 128
#define E_CNT 1000000
#define K_CNT 50000
#define NS_CNT 9
#define CAP 64

#define BM 64
#define NBLK 1563            // ceil(100000/64); padded A rows = 100032

// ---------------- workspace layout (bytes) ----------------
#define OFF_CNT    0                    // U*4 = 400000
#define OFF_BPT    400384               // 512*256*2 = 262144 (bf16, permuted+transposed+swizzled)
#define OFF_BSUM   662528               // 512*4 = 2048 (f32, bsum_p[dim*4+gate])
#define OFF_BUCKET 665600               // U*CAP*4 = 25600000
#define OFF_ABF    26265600             // 100032 rows * 256 bf16 = 51216384 ; h (f32) aliases this
// end ~77.5MB

typedef __attribute__((ext_vector_type(8))) short bf16x8;
typedef __attribute__((ext_vector_type(4))) float f32x4;

__device__ __forceinline__ unsigned short f2bf(float f) {
    unsigned u = __builtin_bit_cast(unsigned, f);
    u = (u + 0x7FFF + ((u >> 16) & 1)) >> 16;   // RNE; inputs finite
    return (unsigned short)u;
}

__device__ __forceinline__ void gload16(const void* g, void* l) {
    __builtin_amdgcn_global_load_lds(
        (const __attribute__((address_space(1))) unsigned int*)g,
        (__attribute__((address_space(3))) unsigned int*)l, 16, 0, 0);
}

__global__ void k_zero(int* __restrict__ cnt) {
    int i = blockIdx.x * 256 + threadIdx.x;
    if (i < U_CNT) cnt[i] = 0;
}

// Bpt[col][kp]: col=j'=d*4+g in [0,512); element (col,k) stored at
// kp = (k>>6)*64 + (((k>>3)&7) ^ (col&7))*8 + (k&7).   B[k][j]=W_ih[j][k] / W_hh[j][k-128], j=g*128+d.
__global__ void k_prep(const float* __restrict__ Wih, const float* __restrict__ Whh,
                       const float* __restrict__ bih, const float* __restrict__ bhh,
                       unsigned short* __restrict__ Bpt, float* __restrict__ bsum_p) {
    int idx = blockIdx.x * 256 + threadIdx.x;
    if (idx < 512) {
        int dim = idx >> 2, g = idx & 3;
        bsum_p[idx] = bih[g * 128 + dim] + bhh[g * 128 + dim];
    }
    if (idx >= 512 * 256) return;
    int col = idx >> 8, kp = idx & 255;
    int seg = kp >> 6, gst = (kp >> 3) & 7, e = kp & 7;
    int k = seg * 64 + (gst ^ (col & 7)) * 8 + e;
    int d = col >> 2, g = col & 3;
    int j = g * 128 + d;
    float v = (k < 128) ? Wih[j * 128 + k] : Whh[j * 128 + (k - 128)];
    Bpt[idx] = f2bf(v);
}

__global__ void k_bucket(const int* __restrict__ dst, int* __restrict__ cnt,
                         int* __restrict__ bucket) {
    int e = blockIdx.x * 256 + threadIdx.x;
    if (e >= E_CNT) return;
    int d = dst[e];
    int slot = atomicAdd(&cnt[d], 1);
    if (slot < CAP) bucket[d * CAP + slot] = e;
}

// one wave per user; lane l holds dims {2l,2l+1}. Writes Abf[u][256] bf16:
// k<128 -> x = user_emb + mean_msg ; k>=128 -> user_emb. Swizzled: within each 64-k
// segment, granule gr=(k>>3)&7 stored at gr^(u&7).
__global__ void k_agg(const float* __restrict__ user_emb, const float* __restrict__ news_emb,
                      const float* __restrict__ cat_emb, const int* __restrict__ esrc,
                      const int* __restrict__ ecat, const int* __restrict__ cnt,
                      const int* __restrict__ bucket, unsigned short* __restrict__ Abf) {
    int wid  = (blockIdx.x * blockDim.x + threadIdx.x) >> 6;
    int lane = threadIdx.x & 63;
    if (wid >= U_CNT) return;
    int deg = cnt[wid];
    if (deg > CAP) deg = CAP;
    const float2* news2 = (const float2*)news_emb;
    const float2* cat2  = (const float2*)cat_emb;
    float2 acc = {0.f, 0.f};
    for (int t = 0; t < deg; ++t) {
        int e = bucket[wid * CAP + t];
        int s = esrc[e];
        int c = ecat[e];
        float2 nv = news2[(size_t)s * 64 + lane];
        float2 cv = cat2[c * 64 + lane];
        acc.x += nv.x * cv.x;
        acc.y += nv.y * cv.y;
    }
    float inv = 1.0f / (float)(deg < 1 ? 1 : deg);
    float2 ue = ((const float2*)user_emb)[(size_t)wid * 64 + lane];
    float2 xv = {ue.x + acc.x * inv, ue.y + acc.y * inv};

    int kl   = 2 * lane;                 // k within 128-dim half
    int seg  = kl >> 6;
    int gr   = (kl >> 3) & 7;
    int e0   = kl & 7;
    int swz  = gr ^ (wid & 7);
    size_t base = (size_t)wid * 256;
    unsigned short* p0 = Abf + base + 0   + seg * 64 + swz * 8 + e0;  // x half
    unsigned short* p1 = Abf + base + 128 + seg * 64 + swz * 8 + e0;  // user_emb half
    *(ushort2*)p0 = make_ushort2(f2bf(xv.x), f2bf(xv.y));
    *(ushort2*)p1 = make_ushort2(f2bf(ue.x), f2bf(ue.y));
}

// MFMA GEMM: gates[64 x 512] = A[64 x 256] @ B[256 x 512] (bf16->f32), fused LSTM.
// 8 waves, wave w owns cols [w*64, w*64+64) in permuted j'=dim*4+gate space.
__global__ __launch_bounds__(512, 4) void k_gemm_lstm(
    const unsigned short* __restrict__ Abf, const unsigned short* __restrict__ Bpt,
    const float* __restrict__ bsum_p, const float* __restrict__ cx,
    float* __restrict__ hout)   // aliases Abf region (f32 [u][128])
{
    __shared__ __align__(16) char smem[8192 + 65536];   // As 64x64bf16 @0, Bs 512x64bf16 @8192
    int t = threadIdx.x, l = t & 63, w = t >> 6;
    int u0 = blockIdx.x * BM;
    int wn0 = w * 64;

    f32x4 acc[4][4];
#pragma unroll
    for (int m = 0; m < 4; ++m)
#pragma unroll
        for (int n = 0; n < 4; ++n) acc[m][n] = (f32x4){0.f, 0.f, 0.f, 0.f};

    int lhi = l >> 3, llo = l & 7;
    for (int step = 0; step < 4; ++step) {
        int k0 = step * 64;
        // stage: A = 8 instrs (8 rows each), B = 64 instrs (8 cols each); wave w gets 9
#pragma unroll
        for (int ii = 0; ii < 9; ++ii) {
            int inst = w * 9 + ii;
            if (inst < 8) {
                int row = inst * 8 + lhi;
                gload16(Abf + (size_t)(u0 + row) * 256 + k0 + llo * 8,
                        smem + inst * 1024);
            } else {
                int b = inst - 8;
                int col = b * 8 + lhi;
                gload16(Bpt + (size_t)col * 256 + k0 + llo * 8,
                        smem + 8192 + b * 1024);
            }
        }
        asm volatile("s_waitcnt vmcnt(0)" ::: "memory");
        __syncthreads();

#pragma unroll
        for (int kf = 0; kf < 2; ++kf) {
            int swz = ((kf * 4 + (l >> 4)) ^ (l & 7)) * 16;
            bf16x8 af[4], bfr[4];
#pragma unroll
            for (int m = 0; m < 4; ++m)
                af[m] = *(const bf16x8*)(smem + (m * 16 + (l & 15)) * 128 + swz);
#pragma unroll
            for (int n = 0; n < 4; ++n)
                bfr[n] = *(const bf16x8*)(smem + 8192 + (wn0 + n * 16 + (l & 15)) * 128 + swz);
#pragma unroll
            for (int m = 0; m < 4; ++m)
#pragma unroll
                for (int n = 0; n < 4; ++n)
                    acc[m][n] = __builtin_amdgcn_mfma_f32_16x16x32_bf16(
                        af[m], bfr[n], acc[m][n], 0, 0, 0);
        }
        __syncthreads();
    }

    // epilogue: per 16-row chunk m: scatter gates to LDS [16][516], then coalesced LSTM
    float* gbuf = (float*)smem;
#pragma unroll 1
    for (int m = 0; m < 4; ++m) {
#pragma unroll
        for (int n = 0; n < 4; ++n)
#pragma unroll
            for (int r = 0; r < 4; ++r)
                gbuf[((l >> 4) * 4 + r) * 516 + wn0 + n * 16 + (l & 15)] = acc[m][n][r];
        __syncthreads();
#pragma unroll
        for (int i = 0; i < 4; ++i) {
            int c = t + 512 * i;          // 16*128 cells
            int row = c >> 7, dim = c & 127;
            int u = u0 + m * 16 + row;
            float4 gv = *(const float4*)&gbuf[row * 516 + dim * 4];
            if (u < U_CNT) {
                float4 bs = *(const float4*)&bsum_p[dim * 4];
                float I = gv.x + bs.x, F = gv.y + bs.y, G = gv.z + bs.z, O = gv.w + bs.w;
                float cxv = cx[(size_t)u * 128 + dim];
                float si = 1.f / (1.f + expf(-I));
                float sf = 1.f / (1.f + expf(-F));
                float so = 1.f / (1.f + expf(-O));
                float cn = sf * cxv + si * tanhf(G);
                hout[(size_t)u * 128 + dim] = so * tanhf(cn);
            }
        }
        __syncthreads();
    }
}

__global__ void k_score(const float* __restrict__ h, const float* __restrict__ news_emb,
                        const int* __restrict__ ns_idx, const int* __restrict__ usi,
                        float* __restrict__ out) {
    int wid  = (blockIdx.x * blockDim.x + threadIdx.x) >> 6;
    int lane = threadIdx.x & 63;
    if (wid >= K_CNT) return;
    int u = usi[wid];
    float2 hv = ((const float2*)h)[(size_t)u * 64 + lane];
    const float2* n2 = (const float2*)news_emb;
    float val = 0.f;
#pragma unroll
    for (int j = 0; j < 9; ++j) {
        int n = ns_idx[wid * 9 + j];
        float2 nv = n2[(size_t)n * 64 + lane];
        float p = hv.x * nv.x + hv.y * nv.y;
#pragma unroll
        for (int off = 32; off; off >>= 1) p += __shfl_xor(p, off, 64);
        if (lane == j) val = p;
    }
    if (lane < 9) out[wid * 9 + lane] = val;
}

extern "C" void kernel_launch(void* const* d_in, const int* in_sizes, int n_in,
                              void* d_out, int out_size, void* d_ws, size_t ws_size,
                              hipStream_t stream) {
    const float* user_emb = (const float*)d_in[0];
    const float* news_emb = (const float*)d_in[1];
    const float* cat_emb  = (const float*)d_in[2];
    const float* cx       = (const float*)d_in[3];
    const float* W_ih     = (const float*)d_in[4];
    const float* W_hh     = (const float*)d_in[5];
    const float* b_ih     = (const float*)d_in[6];
    const float* b_hh     = (const float*)d_in[7];
    const int* edge_src   = (const int*)d_in[8];
    const int* edge_dst   = (const int*)d_in[9];
    const int* edge_cat   = (const int*)d_in[10];
    const int* ns_idx     = (const int*)d_in[11];
    const int* usi        = (const int*)d_in[12];
    float* out = (float*)d_out;

    char* ws = (char*)d_ws;
    int*            cnt    = (int*)(ws + OFF_CNT);
    unsigned short* Bpt    = (unsigned short*)(ws + OFF_BPT);
    float*          bsum_p = (float*)(ws + OFF_BSUM);
    int*            bucket = (int*)(ws + OFF_BUCKET);
    unsigned short* Abf    = (unsigned short*)(ws + OFF_ABF);
    float*          h      = (float*)(ws + OFF_ABF);   // aliases Abf (written post-read)

    k_zero<<<(U_CNT + 255) / 256, 256, 0, stream>>>(cnt);
    k_prep<<<512, 256, 0, stream>>>(W_ih, W_hh, b_ih, b_hh, Bpt, bsum_p);
    k_bucket<<<(E_CNT + 255) / 256, 256, 0, stream>>>(edge_dst, cnt, bucket);
    k_agg<<<25000, 256, 0, stream>>>(user_emb, news_emb, cat_emb, edge_src, edge_cat,
                                     cnt, bucket, Abf);
    k_gemm_lstm<<<NBLK, 512, 0, stream>>>(Abf, Bpt, bsum_p, cx, h);
    k_score<<<(K_CNT * 64 + 255) / 256, 256, 0, stream>>>(h, news_emb, ns_idx, usi, out);
}

// Round 4
// 572.752 us; speedup vs baseline: 1.6201x; 1.3920x over previous
//
#include <hip/hip_runtime.h>
#include <math.h>

#define U_CNT 100000
#define N_CNT 50000
#define C_CNT 20
#define D_DIM 128
#define E_CNT 1000000
#define K_CNT 50000
#define NS_CNT 9
#define CAP 64

#define BM 64
#define NBLK 1563            // ceil(100000/64); padded A rows = 100032

// ---------------- workspace layout (bytes) ----------------
#define OFF_CNT    0                    // U*4 = 400000
#define OFF_BPT    400384               // 512*256*2 = 262144 (bf16, permuted+transposed+swizzled)
#define OFF_BSUM   662528               // 512*4 = 2048 (f32, bsum_p[dim*4+gate])
#define OFF_BUCKET 665600               // U*CAP*4 = 25600000
#define OFF_ABF    26265600             // 100032 rows * 256 bf16 = 51216384 ; h (f32) aliases this
// end ~77.5MB

typedef __attribute__((ext_vector_type(8))) short bf16x8;
typedef __attribute__((ext_vector_type(4))) float f32x4;

__device__ __forceinline__ unsigned short f2bf(float f) {
    unsigned u = __builtin_bit_cast(unsigned, f);
    u = (u + 0x7FFF + ((u >> 16) & 1)) >> 16;   // RNE; inputs finite
    return (unsigned short)u;
}

__device__ __forceinline__ void gload16(const void* g, void* l) {
    __builtin_amdgcn_global_load_lds(
        (const __attribute__((address_space(1))) unsigned int*)g,
        (__attribute__((address_space(3))) unsigned int*)l, 16, 0, 0);
}

__global__ void k_zero(int* __restrict__ cnt) {
    int i = blockIdx.x * 256 + threadIdx.x;
    if (i < U_CNT) cnt[i] = 0;
}

// Bpt[col][kp]: col=j'=d*4+g in [0,512); element (col,k) stored at
// kp = (k>>6)*64 + (((k>>3)&7) ^ (col&7))*8 + (k&7).   B[k][j]=W_ih[j][k] / W_hh[j][k-128], j=g*128+d.
__global__ void k_prep(const float* __restrict__ Wih, const float* __restrict__ Whh,
                       const float* __restrict__ bih, const float* __restrict__ bhh,
                       unsigned short* __restrict__ Bpt, float* __restrict__ bsum_p) {
    int idx = blockIdx.x * 256 + threadIdx.x;
    if (idx < 512) {
        int dim = idx >> 2, g = idx & 3;
        bsum_p[idx] = bih[g * 128 + dim] + bhh[g * 128 + dim];
    }
    if (idx >= 512 * 256) return;
    int col = idx >> 8, kp = idx & 255;
    int seg = kp >> 6, gst = (kp >> 3) & 7, e = kp & 7;
    int k = seg * 64 + (gst ^ (col & 7)) * 8 + e;
    int d = col >> 2, g = col & 3;
    int j = g * 128 + d;
    float v = (k < 128) ? Wih[j * 128 + k] : Whh[j * 128 + (k - 128)];
    Bpt[idx] = f2bf(v);
}

__global__ void k_bucket(const int* __restrict__ dst, int* __restrict__ cnt,
                         int* __restrict__ bucket) {
    int e = blockIdx.x * 256 + threadIdx.x;
    if (e >= E_CNT) return;
    int d = dst[e];
    int slot = atomicAdd(&cnt[d], 1);
    if (slot < CAP) bucket[d * CAP + slot] = e;
}

// one wave per user; lane l holds dims {2l,2l+1}. Writes Abf[u][256] bf16:
// k<128 -> x = user_emb + mean_msg ; k>=128 -> user_emb. Swizzled: within each 64-k
// segment, granule gr=(k>>3)&7 stored at gr^(u&7).
__global__ void k_agg(const float* __restrict__ user_emb, const float* __restrict__ news_emb,
                      const float* __restrict__ cat_emb, const int* __restrict__ esrc,
                      const int* __restrict__ ecat, const int* __restrict__ cnt,
                      const int* __restrict__ bucket, unsigned short* __restrict__ Abf) {
    int wid  = (blockIdx.x * blockDim.x + threadIdx.x) >> 6;
    int lane = threadIdx.x & 63;
    if (wid >= U_CNT) return;
    int deg = cnt[wid];
    if (deg > CAP) deg = CAP;
    const float2* news2 = (const float2*)news_emb;
    const float2* cat2  = (const float2*)cat_emb;
    float2 acc = {0.f, 0.f};
    for (int t = 0; t < deg; ++t) {
        int e = bucket[wid * CAP + t];
        int s = esrc[e];
        int c = ecat[e];
        float2 nv = news2[(size_t)s * 64 + lane];
        float2 cv = cat2[c * 64 + lane];
        acc.x += nv.x * cv.x;
        acc.y += nv.y * cv.y;
    }
    float inv = 1.0f / (float)(deg < 1 ? 1 : deg);
    float2 ue = ((const float2*)user_emb)[(size_t)wid * 64 + lane];
    float2 xv = {ue.x + acc.x * inv, ue.y + acc.y * inv};

    int kl   = 2 * lane;                 // k within 128-dim half
    int seg  = kl >> 6;
    int gr   = (kl >> 3) & 7;
    int e0   = kl & 7;
    int swz  = gr ^ (wid & 7);
    size_t base = (size_t)wid * 256;
    unsigned short* p0 = Abf + base + 0   + seg * 64 + swz * 8 + e0;  // x half
    unsigned short* p1 = Abf + base + 128 + seg * 64 + swz * 8 + e0;  // user_emb half
    *(ushort2*)p0 = make_ushort2(f2bf(xv.x), f2bf(xv.y));
    *(ushort2*)p1 = make_ushort2(f2bf(ue.x), f2bf(ue.y));
}

// MFMA GEMM: gates[64 x 512] = A[64 x 256] @ B[256 x 512] (bf16->f32), fused LSTM.
// 8 waves, wave w owns cols [w*64, w*64+64) in permuted j'=dim*4+gate space.
// NOTE: epilogue m-loop is FULLY unrolled — runtime indexing of acc[][] demotes the
// whole accumulator array to scratch (rule #20; round-2 showed 1.2GB of spill writes).
__global__ __launch_bounds__(512, 4) void k_gemm_lstm(
    const unsigned short* __restrict__ Abf, const unsigned short* __restrict__ Bpt,
    const float* __restrict__ bsum_p, const float* __restrict__ cx,
    float* __restrict__ hout)   // aliases Abf region (f32 [u][128])
{
    __shared__ __align__(16) char smem[8192 + 65536];   // As 64x64bf16 @0, Bs 512x64bf16 @8192
    int t = threadIdx.x, l = t & 63, w = t >> 6;
    int u0 = blockIdx.x * BM;
    int wn0 = w * 64;

    f32x4 acc[4][4];
#pragma unroll
    for (int m = 0; m < 4; ++m)
#pragma unroll
        for (int n = 0; n < 4; ++n) acc[m][n] = (f32x4){0.f, 0.f, 0.f, 0.f};

    int lhi = l >> 3, llo = l & 7;
    for (int step = 0; step < 4; ++step) {
        int k0 = step * 64;
        // stage: A = 8 instrs (8 rows each), B = 64 instrs (8 cols each); wave w gets 9
#pragma unroll
        for (int ii = 0; ii < 9; ++ii) {
            int inst = w * 9 + ii;
            if (inst < 8) {
                int row = inst * 8 + lhi;
                gload16(Abf + (size_t)(u0 + row) * 256 + k0 + llo * 8,
                        smem + inst * 1024);
            } else {
                int b = inst - 8;
                int col = b * 8 + lhi;
                gload16(Bpt + (size_t)col * 256 + k0 + llo * 8,
                        smem + 8192 + b * 1024);
            }
        }
        asm volatile("s_waitcnt vmcnt(0)" ::: "memory");
        __syncthreads();

#pragma unroll
        for (int kf = 0; kf < 2; ++kf) {
            int swz = ((kf * 4 + (l >> 4)) ^ (l & 7)) * 16;
            bf16x8 af[4], bfr[4];
#pragma unroll
            for (int m = 0; m < 4; ++m)
                af[m] = *(const bf16x8*)(smem + (m * 16 + (l & 15)) * 128 + swz);
#pragma unroll
            for (int n = 0; n < 4; ++n)
                bfr[n] = *(const bf16x8*)(smem + 8192 + (wn0 + n * 16 + (l & 15)) * 128 + swz);
#pragma unroll
            for (int m = 0; m < 4; ++m)
#pragma unroll
                for (int n = 0; n < 4; ++n)
                    acc[m][n] = __builtin_amdgcn_mfma_f32_16x16x32_bf16(
                        af[m], bfr[n], acc[m][n], 0, 0, 0);
        }
        __syncthreads();
    }

    // epilogue: per 16-row chunk m: scatter gates to LDS [16][516], then coalesced LSTM
    float* gbuf = (float*)smem;
#pragma unroll
    for (int m = 0; m < 4; ++m) {
#pragma unroll
        for (int n = 0; n < 4; ++n)
#pragma unroll
            for (int r = 0; r < 4; ++r)
                gbuf[((l >> 4) * 4 + r) * 516 + wn0 + n * 16 + (l & 15)] = acc[m][n][r];
        __syncthreads();
#pragma unroll
        for (int i = 0; i < 4; ++i) {
            int c = t + 512 * i;          // 16*128 cells
            int row = c >> 7, dim = c & 127;
            int u = u0 + m * 16 + row;
            float4 gv = *(const float4*)&gbuf[row * 516 + dim * 4];
            if (u < U_CNT) {
                float4 bs = *(const float4*)&bsum_p[dim * 4];
                float I = gv.x + bs.x, F = gv.y + bs.y, G = gv.z + bs.z, O = gv.w + bs.w;
                float cxv = cx[(size_t)u * 128 + dim];
                float si = 1.f / (1.f + expf(-I));
                float sf = 1.f / (1.f + expf(-F));
                float so = 1.f / (1.f + expf(-O));
                float cn = sf * cxv + si * tanhf(G);
                hout[(size_t)u * 128 + dim] = so * tanhf(cn);
            }
        }
        __syncthreads();
    }
}

__global__ void k_score(const float* __restrict__ h, const float* __restrict__ news_emb,
                        const int* __restrict__ ns_idx, const int* __restrict__ usi,
                        float* __restrict__ out) {
    int wid  = (blockIdx.x * blockDim.x + threadIdx.x) >> 6;
    int lane = threadIdx.x & 63;
    if (wid >= K_CNT) return;
    int u = usi[wid];
    float2 hv = ((const float2*)h)[(size_t)u * 64 + lane];
    const float2* n2 = (const float2*)news_emb;
    float val = 0.f;
#pragma unroll
    for (int j = 0; j < 9; ++j) {
        int n = ns_idx[wid * 9 + j];
        float2 nv = n2[(size_t)n * 64 + lane];
        float p = hv.x * nv.x + hv.y * nv.y;
#pragma unroll
        for (int off = 32; off; off >>= 1) p += __shfl_xor(p, off, 64);
        if (lane == j) val = p;
    }
    if (lane < 9) out[wid * 9 + lane] = val;
}

extern "C" void kernel_launch(void* const* d_in, const int* in_sizes, int n_in,
                              void* d_out, int out_size, void* d_ws, size_t ws_size,
                              hipStream_t stream) {
    const float* user_emb = (const float*)d_in[0];
    const float* news_emb = (const float*)d_in[1];
    const float* cat_emb  = (const float*)d_in[2];
    const float* cx       = (const float*)d_in[3];
    const float* W_ih     = (const float*)d_in[4];
    const float* W_hh     = (const float*)d_in[5];
    const float* b_ih     = (const float*)d_in[6];
    const float* b_hh     = (const float*)d_in[7];
    const int* edge_src   = (const int*)d_in[8];
    const int* edge_dst   = (const int*)d_in[9];
    const int* edge_cat   = (const int*)d_in[10];
    const int* ns_idx     = (const int*)d_in[11];
    const int* usi        = (const int*)d_in[12];
    float* out = (float*)d_out;

    char* ws = (char*)d_ws;
    int*            cnt    = (int*)(ws + OFF_CNT);
    unsigned short* Bpt    = (unsigned short*)(ws + OFF_BPT);
    float*          bsum_p = (float*)(ws + OFF_BSUM);
    int*            bucket = (int*)(ws + OFF_BUCKET);
    unsigned short* Abf    = (unsigned short*)(ws + OFF_ABF);
    float*          h      = (float*)(ws + OFF_ABF);   // aliases Abf (written post-read)

    k_zero<<<(U_CNT + 255) / 256, 256, 0, stream>>>(cnt);
    k_prep<<<512, 256, 0, stream>>>(W_ih, W_hh, b_ih, b_hh, Bpt, bsum_p);
    k_bucket<<<(E_CNT + 255) / 256, 256, 0, stream>>>(edge_dst, cnt, bucket);
    k_agg<<<25000, 256, 0, stream>>>(user_emb, news_emb, cat_emb, edge_src, edge_cat,
                                     cnt, bucket, Abf);
    k_gemm_lstm<<<NBLK, 512, 0, stream>>>(Abf, Bpt, bsum_p, cx, h);
    k_score<<<(K_CNT * 64 + 255) / 256, 256, 0, stream>>>(h, news_emb, ns_idx, usi, out);
}

// Round 6
// 468.442 us; speedup vs baseline: 1.9809x; 1.2227x over previous
//
#include <hip/hip_runtime.h>
#include <math.h>

#define U_CNT 100000
#define N_CNT 50000
#define C_CNT 20
#define D_DIM 128
#define E_CNT 1000000
#define K_CNT 50000
#define NS_CNT 9
#define CAP 64

#define BM 64
#define NBLK 1563            // ceil(100000/64); padded A rows = 100032

// ---------------- workspace layout (bytes) ----------------
#define OFF_CNT    0                    // U*4 = 400000
#define OFF_BPT    400384               // 512*256*2 = 262144 (bf16 B, permuted+transposed+swizzled)
#define OFF_BSUM   662528               // 512*4 = 2048
#define OFF_NBF    665600               // 50000*128*2 = 12800000 (bf16 news)
#define OFF_BUCKET 13465600             // U*CAP*4 = 25600000 (packed src|cat<<16)
#define OFF_ABF    39065664             // 100032*256*2 = 51216384 ; h (f32) aliases this
// end ~90.3MB

typedef __attribute__((ext_vector_type(8))) short bf16x8;
typedef __attribute__((ext_vector_type(4))) float f32x4;

__device__ __forceinline__ unsigned short f2bf(float f) {
    unsigned u = __builtin_bit_cast(unsigned, f);
    u = (u + 0x7FFF + ((u >> 16) & 1)) >> 16;   // RNE; inputs finite
    return (unsigned short)u;
}
__device__ __forceinline__ float bf2f(unsigned short b) {
    return __builtin_bit_cast(float, (unsigned)b << 16);
}

__device__ __forceinline__ void gload16(const void* g, void* l) {
    __builtin_amdgcn_global_load_lds(
        (const __attribute__((address_space(1))) unsigned int*)g,
        (__attribute__((address_space(3))) unsigned int*)l, 16, 0, 0);
}

__global__ void k_zero(int* __restrict__ cnt) {
    int i = blockIdx.x * 256 + threadIdx.x;
    if (i < U_CNT) cnt[i] = 0;
}

// Bpt[col][kp]: col=j'=d*4+g; element (col,k) at kp=(k>>6)*64+(((k>>3)&7)^(col&7))*8+(k&7)
__global__ void k_prep(const float* __restrict__ Wih, const float* __restrict__ Whh,
                       const float* __restrict__ bih, const float* __restrict__ bhh,
                       unsigned short* __restrict__ Bpt, float* __restrict__ bsum_p) {
    int idx = blockIdx.x * 256 + threadIdx.x;
    if (idx < 512) {
        int dim = idx >> 2, g = idx & 3;
        bsum_p[idx] = bih[g * 128 + dim] + bhh[g * 128 + dim];
    }
    if (idx >= 512 * 256) return;
    int col = idx >> 8, kp = idx & 255;
    int seg = kp >> 6, gst = (kp >> 3) & 7, e = kp & 7;
    int k = seg * 64 + (gst ^ (col & 7)) * 8 + e;
    int d = col >> 2, g = col & 3;
    int j = g * 128 + d;
    float v = (k < 128) ? Wih[j * 128 + k] : Whh[j * 128 + (k - 128)];
    Bpt[idx] = f2bf(v);
}

// news f32 -> bf16 copy (halves k_agg gather bytes)
__global__ void k_nbf(const float* __restrict__ news, unsigned short* __restrict__ nbf) {
    int i = blockIdx.x * 256 + threadIdx.x;     // 1.6M float4 groups
    if (i >= N_CNT * 32) return;
    float4 v = ((const float4*)news)[i];
    ushort4 o = {f2bf(v.x), f2bf(v.y), f2bf(v.z), f2bf(v.w)};
    ((ushort4*)nbf)[i] = o;
}

// bucket entry = src | (cat<<16): kills the esrc/ecat indirection in k_agg
__global__ void k_bucket(const int* __restrict__ dst, const int* __restrict__ esrc,
                         const int* __restrict__ ecat, int* __restrict__ cnt,
                         int* __restrict__ bucket) {
    int e = blockIdx.x * 256 + threadIdx.x;
    if (e >= E_CNT) return;
    int d = dst[e];
    int slot = atomicAdd(&cnt[d], 1);
    if (slot < CAP) bucket[d * CAP + slot] = (esrc[e] & 0xFFFF) | (ecat[e] << 16);
}

// one wave per user, half-wave edge parallelism: lanes 0-31 even edges, 32-63 odd.
// lane lid holds dims 4*lid..4*lid+3. Manual 1-deep software pipeline on the packed load.
__global__ void k_agg(const float* __restrict__ user_emb,
                      const unsigned short* __restrict__ news_bf,
                      const float* __restrict__ cat_emb,
                      const int* __restrict__ cnt,
                      const int* __restrict__ bucket,
                      unsigned short* __restrict__ Abf) {
    int wid  = (blockIdx.x * blockDim.x + threadIdx.x) >> 6;
    int lane = threadIdx.x & 63;
    if (wid >= U_CNT) return;
    int deg = cnt[wid];
    if (deg > CAP) deg = CAP;
    int half = lane >> 5, lid = lane & 31;
    const int* bp = bucket + wid * CAP;
    float4 acc = {0.f, 0.f, 0.f, 0.f};
    int trips = (deg + 1) >> 1;
    int p = 0; float vmask = 0.f;
    if (trips > 0) {
        int e0 = half;
        p = bp[e0 < deg ? e0 : 0];
        vmask = (e0 < deg) ? 1.f : 0.f;
    }
    for (int t = 0; t < trips; ++t) {
        int en = 2 * (t + 1) + half;
        int pn = 0; float vn = 0.f;
        if (t + 1 < trips) {
            pn = bp[en < deg ? en : 0];
            vn = (en < deg) ? 1.f : 0.f;
        }
        int s = p & 0xFFFF;
        int c = p >> 16;
        ushort4 nv = *(const ushort4*)&news_bf[(size_t)s * 128 + lid * 4];
        float4  cv = *(const float4*)&cat_emb[c * 128 + lid * 4];
        acc.x += vmask * bf2f(nv.x) * cv.x;
        acc.y += vmask * bf2f(nv.y) * cv.y;
        acc.z += vmask * bf2f(nv.z) * cv.z;
        acc.w += vmask * bf2f(nv.w) * cv.w;
        p = pn; vmask = vn;
    }
    acc.x += __shfl_xor(acc.x, 32, 64);
    acc.y += __shfl_xor(acc.y, 32, 64);
    acc.z += __shfl_xor(acc.z, 32, 64);
    acc.w += __shfl_xor(acc.w, 32, 64);
    if (half == 0) {
        float inv = 1.0f / (float)(deg < 1 ? 1 : deg);
        float4 ue = *(const float4*)&user_emb[(size_t)wid * 128 + lid * 4];
        float4 xv = {ue.x + acc.x * inv, ue.y + acc.y * inv,
                     ue.z + acc.z * inv, ue.w + acc.w * inv};
        // swizzled bf16 store matching k_gemm_lstm's gload16-linear LDS layout
        int seg = lid >> 4;                 // d>>6 for d=4*lid
        int gr  = (lid >> 1) & 7;           // (d>>3)&7
        int eo  = (lid & 1) * 4;            // d&7
        int pos = seg * 64 + ((gr ^ (wid & 7)) * 8) + eo;
        size_t base = (size_t)wid * 256;
        ushort4 xb = {f2bf(xv.x), f2bf(xv.y), f2bf(xv.z), f2bf(xv.w)};
        ushort4 ub = {f2bf(ue.x), f2bf(ue.y), f2bf(ue.z), f2bf(ue.w)};
        *(ushort4*)&Abf[base + pos] = xb;
        *(ushort4*)&Abf[base + 128 + pos] = ub;
    }
}

// MFMA GEMM: gates[64x512] = A[64x256] @ B[256x512] (bf16->f32), fused LSTM epilogue.
// Epilogue fully unrolled — runtime acc[][] indexing demotes accumulators to scratch (rule #20).
__global__ __launch_bounds__(512, 4) void k_gemm_lstm(
    const unsigned short* __restrict__ Abf, const unsigned short* __restrict__ Bpt,
    const float* __restrict__ bsum_p, const float* __restrict__ cx,
    float* __restrict__ hout)
{
    __shared__ __align__(16) char smem[8192 + 65536];   // As 64x64bf16 @0, Bs 512x64bf16 @8192
    int t = threadIdx.x, l = t & 63, w = t >> 6;
    int u0 = blockIdx.x * BM;
    int wn0 = w * 64;

    f32x4 acc[4][4];
#pragma unroll
    for (int m = 0; m < 4; ++m)
#pragma unroll
        for (int n = 0; n < 4; ++n) acc[m][n] = (f32x4){0.f, 0.f, 0.f, 0.f};

    int lhi = l >> 3, llo = l & 7;
    for (int step = 0; step < 4; ++step) {
        int k0 = step * 64;
#pragma unroll
        for (int ii = 0; ii < 9; ++ii) {
            int inst = w * 9 + ii;
            if (inst < 8) {
                int row = inst * 8 + lhi;
                gload16(Abf + (size_t)(u0 + row) * 256 + k0 + llo * 8,
                        smem + inst * 1024);
            } else {
                int b = inst - 8;
                int col = b * 8 + lhi;
                gload16(Bpt + (size_t)col * 256 + k0 + llo * 8,
                        smem + 8192 + b * 1024);
            }
        }
        asm volatile("s_waitcnt vmcnt(0)" ::: "memory");
        __syncthreads();

#pragma unroll
        for (int kf = 0; kf < 2; ++kf) {
            int swz = ((kf * 4 + (l >> 4)) ^ (l & 7)) * 16;
            bf16x8 af[4], bfr[4];
#pragma unroll
            for (int m = 0; m < 4; ++m)
                af[m] = *(const bf16x8*)(smem + (m * 16 + (l & 15)) * 128 + swz);
#pragma unroll
            for (int n = 0; n < 4; ++n)
                bfr[n] = *(const bf16x8*)(smem + 8192 + (wn0 + n * 16 + (l & 15)) * 128 + swz);
#pragma unroll
            for (int m = 0; m < 4; ++m)
#pragma unroll
                for (int n = 0; n < 4; ++n)
                    acc[m][n] = __builtin_amdgcn_mfma_f32_16x16x32_bf16(
                        af[m], bfr[n], acc[m][n], 0, 0, 0);
        }
        __syncthreads();
    }

    float* gbuf = (float*)smem;
#pragma unroll
    for (int m = 0; m < 4; ++m) {
#pragma unroll
        for (int n = 0; n < 4; ++n)
#pragma unroll
            for (int r = 0; r < 4; ++r)
                gbuf[((l >> 4) * 4 + r) * 516 + wn0 + n * 16 + (l & 15)] = acc[m][n][r];
        __syncthreads();
#pragma unroll
        for (int i = 0; i < 4; ++i) {
            int c = t + 512 * i;
            int row = c >> 7, dim = c & 127;
            int u = u0 + m * 16 + row;
            float4 gv = *(const float4*)&gbuf[row * 516 + dim * 4];
            if (u < U_CNT) {
                float4 bs = *(const float4*)&bsum_p[dim * 4];
                float I = gv.x + bs.x, F = gv.y + bs.y, G = gv.z + bs.z, O = gv.w + bs.w;
                float cxv = cx[(size_t)u * 128 + dim];
                float si = 1.f / (1.f + expf(-I));
                float sf = 1.f / (1.f + expf(-F));
                float so = 1.f / (1.f + expf(-O));
                float cn = sf * cxv + si * tanhf(G);
                hout[(size_t)u * 128 + dim] = so * tanhf(cn);
            }
        }
        __syncthreads();
    }
}

__global__ void k_score(const float* __restrict__ h, const float* __restrict__ news_emb,
                        const int* __restrict__ ns_idx, const int* __restrict__ usi,
                        float* __restrict__ out) {
    int wid  = (blockIdx.x * blockDim.x + threadIdx.x) >> 6;
    int lane = threadIdx.x & 63;
    if (wid >= K_CNT) return;
    int u = usi[wid];
    float2 hv = ((const float2*)h)[(size_t)u * 64 + lane];
    const float2* n2 = (const float2*)news_emb;
    float val = 0.f;
#pragma unroll
    for (int j = 0; j < 9; ++j) {
        int n = ns_idx[wid * 9 + j];
        float2 nv = n2[(size_t)n * 64 + lane];
        float p = hv.x * nv.x + hv.y * nv.y;
#pragma unroll
        for (int off = 32; off; off >>= 1) p += __shfl_xor(p, off, 64);
        if (lane == j) val = p;
    }
    if (lane < 9) out[wid * 9 + lane] = val;
}

extern "C" void kernel_launch(void* const* d_in, const int* in_sizes, int n_in,
                              void* d_out, int out_size, void* d_ws, size_t ws_size,
                              hipStream_t stream) {
    const float* user_emb = (const float*)d_in[0];
    const float* news_emb = (const float*)d_in[1];
    const float* cat_emb  = (const float*)d_in[2];
    const float* cx       = (const float*)d_in[3];
    const float* W_ih     = (const float*)d_in[4];
    const float* W_hh     = (const float*)d_in[5];
    const float* b_ih     = (const float*)d_in[6];
    const float* b_hh     = (const float*)d_in[7];
    const int* edge_src   = (const int*)d_in[8];
    const int* edge_dst   = (const int*)d_in[9];
    const int* edge_cat   = (const int*)d_in[10];
    const int* ns_idx     = (const int*)d_in[11];
    const int* usi        = (const int*)d_in[12];
    float* out = (float*)d_out;

    char* ws = (char*)d_ws;
    int*            cnt    = (int*)(ws + OFF_CNT);
    unsigned short* Bpt    = (unsigned short*)(ws + OFF_BPT);
    float*          bsum_p = (float*)(ws + OFF_BSUM);
    unsigned short* nbf    = (unsigned short*)(ws + OFF_NBF);
    int*            bucket = (int*)(ws + OFF_BUCKET);
    unsigned short* Abf    = (unsigned short*)(ws + OFF_ABF);
    float*          h      = (float*)(ws + OFF_ABF);   // aliases Abf (written post-read)

    k_zero<<<(U_CNT + 255) / 256, 256, 0, stream>>>(cnt);
    k_prep<<<512, 256, 0, stream>>>(W_ih, W_hh, b_ih, b_hh, Bpt, bsum_p);
    k_nbf<<<6250, 256, 0, stream>>>(news_emb, nbf);
    k_bucket<<<(E_CNT + 255) / 256, 256, 0, stream>>>(edge_dst, edge_src, edge_cat, cnt, bucket);
    k_agg<<<25000, 256, 0, stream>>>(user_emb, nbf, cat_emb, cnt, bucket, Abf);
    k_gemm_lstm<<<NBLK, 512, 0, stream>>>(Abf, Bpt, bsum_p, cx, h);
    k_score<<<(K_CNT * 64 + 255) / 256, 256, 0, stream>>>(h, news_emb, ns_idx, usi, out);
}

// Round 8
// 427.253 us; speedup vs baseline: 2.1719x; 1.0964x over previous
//
#include <hip/hip_runtime.h>
#include <math.h>

#define U_CNT 100000
#define N_CNT 50000
#define C_CNT 20
#define D_DIM 128
#define E_CNT 1000000
#define K_CNT 50000
#define NS_CNT 9
#define CAP 64

#define BM 64
#define NBLK 1563            // ceil(100000/64); padded A rows = 100032

// ---------------- workspace layout (bytes) ----------------
#define OFF_CNT    0                    // U*4 = 400000
#define OFF_BPT    400384               // 512*256*2 = 262144 (bf16 B, permuted+transposed+swizzled)
#define OFF_BSUM   662528               // 512*4 = 2048
#define OFF_NBF    665600               // 50000*128*2 = 12800000 (bf16 news)
#define OFF_BUCKET 13465600             // U*CAP*4 = 25600000 (packed src|cat<<16)
#define OFF_ABF    39065664             // 100032*256*2 = 51216384 ; h_bf16 row-aligned alias
// end ~90.3MB

typedef __attribute__((ext_vector_type(8))) short bf16x8;
typedef __attribute__((ext_vector_type(4))) float f32x4;

__device__ __forceinline__ unsigned short f2bf(float f) {
    unsigned u = __builtin_bit_cast(unsigned, f);
    u = (u + 0x7FFF + ((u >> 16) & 1)) >> 16;   // RNE; inputs finite
    return (unsigned short)u;
}
__device__ __forceinline__ float bf2f(unsigned short b) {
    return __builtin_bit_cast(float, (unsigned)b << 16);
}

// fast sigmoid/tanh: v_exp_f32 + v_rcp_f32 (~1ulp each) instead of libm exp/tanh +
// full-IEEE divides (~150 VALU/cell -> ~32). Round-6 showed epilogue VALU ~30us.
__device__ __forceinline__ float sig_fast(float x) {
    float t = __builtin_amdgcn_exp2f(x * -1.44269504f);
    return __builtin_amdgcn_rcpf(1.f + t);     // x=-inf path: rcp(inf)=0, correct
}
__device__ __forceinline__ float tanh_fast(float x) {
    x = fminf(fmaxf(x, -15.f), 15.f);          // avoid inf*0=NaN
    float t = __builtin_amdgcn_exp2f(x * 2.88539008f);
    return (t - 1.f) * __builtin_amdgcn_rcpf(t + 1.f);
}

__device__ __forceinline__ void gload16(const void* g, void* l) {
    __builtin_amdgcn_global_load_lds(
        (const __attribute__((address_space(1))) unsigned int*)g,
        (__attribute__((address_space(3))) unsigned int*)l, 16, 0, 0);
}

__global__ void k_zero(int* __restrict__ cnt) {
    int i = blockIdx.x * 256 + threadIdx.x;
    if (i < U_CNT) cnt[i] = 0;
}

// Bpt[col][kp]: col=j'=d*4+g; element (col,k) at kp=(k>>6)*64+(((k>>3)&7)^(col&7))*8+(k&7)
__global__ void k_prep(const float* __restrict__ Wih, const float* __restrict__ Whh,
                       const float* __restrict__ bih, const float* __restrict__ bhh,
                       unsigned short* __restrict__ Bpt, float* __restrict__ bsum_p) {
    int idx = blockIdx.x * 256 + threadIdx.x;
    if (idx < 512) {
        int dim = idx >> 2, g = idx & 3;
        bsum_p[idx] = bih[g * 128 + dim] + bhh[g * 128 + dim];
    }
    if (idx >= 512 * 256) return;
    int col = idx >> 8, kp = idx & 255;
    int seg = kp >> 6, gst = (kp >> 3) & 7, e = kp & 7;
    int k = seg * 64 + (gst ^ (col & 7)) * 8 + e;
    int d = col >> 2, g = col & 3;
    int j = g * 128 + d;
    float v = (k < 128) ? Wih[j * 128 + k] : Whh[j * 128 + (k - 128)];
    Bpt[idx] = f2bf(v);
}

// news f32 -> bf16 (halves k_agg + k_score gather bytes)
__global__ void k_nbf(const float* __restrict__ news, unsigned short* __restrict__ nbf) {
    int i = blockIdx.x * 256 + threadIdx.x;
    if (i >= N_CNT * 32) return;
    float4 v = ((const float4*)news)[i];
    ushort4 o = {f2bf(v.x), f2bf(v.y), f2bf(v.z), f2bf(v.w)};
    ((ushort4*)nbf)[i] = o;
}

__global__ void k_bucket(const int* __restrict__ dst, const int* __restrict__ esrc,
                         const int* __restrict__ ecat, int* __restrict__ cnt,
                         int* __restrict__ bucket) {
    int e = blockIdx.x * 256 + threadIdx.x;
    if (e >= E_CNT) return;
    int d = dst[e];
    int slot = atomicAdd(&cnt[d], 1);
    if (slot < CAP) bucket[d * CAP + slot] = (esrc[e] & 0xFFFF) | (ecat[e] << 16);
}

// one wave per user, half-wave edge parallelism (unchanged from round 6)
__global__ void k_agg(const float* __restrict__ user_emb,
                      const unsigned short* __restrict__ news_bf,
                      const float* __restrict__ cat_emb,
                      const int* __restrict__ cnt,
                      const int* __restrict__ bucket,
                      unsigned short* __restrict__ Abf) {
    int wid  = (blockIdx.x * blockDim.x + threadIdx.x) >> 6;
    int lane = threadIdx.x & 63;
    if (wid >= U_CNT) return;
    int deg = cnt[wid];
    if (deg > CAP) deg = CAP;
    int half = lane >> 5, lid = lane & 31;
    const int* bp = bucket + wid * CAP;
    float4 acc = {0.f, 0.f, 0.f, 0.f};
    int trips = (deg + 1) >> 1;
    int p = 0; float vmask = 0.f;
    if (trips > 0) {
        int e0 = half;
        p = bp[e0 < deg ? e0 : 0];
        vmask = (e0 < deg) ? 1.f : 0.f;
    }
    for (int t = 0; t < trips; ++t) {
        int en = 2 * (t + 1) + half;
        int pn = 0; float vn = 0.f;
        if (t + 1 < trips) {
            pn = bp[en < deg ? en : 0];
            vn = (en < deg) ? 1.f : 0.f;
        }
        int s = p & 0xFFFF;
        int c = p >> 16;
        ushort4 nv = *(const ushort4*)&news_bf[(size_t)s * 128 + lid * 4];
        float4  cv = *(const float4*)&cat_emb[c * 128 + lid * 4];
        acc.x += vmask * bf2f(nv.x) * cv.x;
        acc.y += vmask * bf2f(nv.y) * cv.y;
        acc.z += vmask * bf2f(nv.z) * cv.z;
        acc.w += vmask * bf2f(nv.w) * cv.w;
        p = pn; vmask = vn;
    }
    acc.x += __shfl_xor(acc.x, 32, 64);
    acc.y += __shfl_xor(acc.y, 32, 64);
    acc.z += __shfl_xor(acc.z, 32, 64);
    acc.w += __shfl_xor(acc.w, 32, 64);
    if (half == 0) {
        float inv = 1.0f / (float)(deg < 1 ? 1 : deg);
        float4 ue = *(const float4*)&user_emb[(size_t)wid * 128 + lid * 4];
        float4 xv = {ue.x + acc.x * inv, ue.y + acc.y * inv,
                     ue.z + acc.z * inv, ue.w + acc.w * inv};
        int seg = lid >> 4;
        int gr  = (lid >> 1) & 7;
        int eo  = (lid & 1) * 4;
        int pos = seg * 64 + ((gr ^ (wid & 7)) * 8) + eo;
        size_t base = (size_t)wid * 256;
        ushort4 xb = {f2bf(xv.x), f2bf(xv.y), f2bf(xv.z), f2bf(xv.w)};
        ushort4 ub = {f2bf(ue.x), f2bf(ue.y), f2bf(ue.z), f2bf(ue.w)};
        *(ushort4*)&Abf[base + pos] = xb;
        *(ushort4*)&Abf[base + 128 + pos] = ub;
    }
}

// MFMA GEMM, BK=32 double-buffered T3 2-phase pipeline: stage(t+1) issued BEFORE
// compute(t); one barrier per step (compiler drains vmcnt at the barrier).
// LDS tiles XOR-swizzled (2-way bank alias = free) via pre-swizzled global sources.
// h written as bf16 at row-stride 256 shorts (row-aligned alias of Abf -> no
// cross-block race). Epilogue: fast sigmoid/tanh, 2 chunks (4 barriers).
#define STAGE(K0, BUF)                                                                   \
    {                                                                                    \
        int bg3 = ((K0) >> 3) & 7;                                                       \
        int seg64 = ((K0) >> 6) * 64;                                                    \
        char* Ab_ = smem + (BUF) * 4096;                                                 \
        char* Bb_ = smem + 8192 + (BUF) * 32768;                                         \
        _Pragma("unroll")                                                                \
        for (int ii = 0; ii < 5; ++ii) {                                                 \
            int inst = w + ii * 8;                                                       \
            if (inst < 4) {                                                              \
                int row = inst * 16 + (l >> 2);                                          \
                int kg = (l & 3) ^ (row & 3);                                            \
                gload16(Abf + (size_t)(u0 + row) * 256 + seg64 +                         \
                            ((bg3 + kg) ^ (row & 7)) * 8,                                \
                        Ab_ + inst * 1024 + l * 16);                                     \
            } else if (inst < 36) {                                                      \
                int b = inst - 4;                                                        \
                int col = b * 16 + (l >> 2);                                             \
                int kg = (l & 3) ^ (col & 3);                                            \
                gload16(Bpt + (size_t)col * 256 + seg64 +                                \
                            ((bg3 + kg) ^ (col & 7)) * 8,                                \
                        Bb_ + b * 1024 + l * 16);                                        \
            }                                                                            \
        }                                                                                \
    }

__global__ __launch_bounds__(512, 4) void k_gemm_lstm(
    const unsigned short* __restrict__ Abf, const unsigned short* __restrict__ Bpt,
    const float* __restrict__ bsum_p, const float* __restrict__ cx,
    unsigned short* __restrict__ hout)   // bf16, stride 256 shorts/row (aliases Abf)
{
    __shared__ __align__(16) char smem[73728];  // A dbuf 2x4KB @0, B dbuf 2x32KB @8192
    int t = threadIdx.x, l = t & 63, w = t >> 6;
    int u0 = blockIdx.x * BM;
    int wn0 = w * 64;

    f32x4 acc[4][4];
#pragma unroll
    for (int m = 0; m < 4; ++m)
#pragma unroll
        for (int n = 0; n < 4; ++n) acc[m][n] = (f32x4){0.f, 0.f, 0.f, 0.f};

    STAGE(0, 0);
    __syncthreads();

#pragma unroll
    for (int step = 0; step < 8; ++step) {
        int cur = step & 1;
        if (step < 7) STAGE((step + 1) * 32, cur ^ 1);   // prefetch next K-slice
        const char* Ab = smem + cur * 4096;
        const char* Bb = smem + 8192 + cur * 32768;
        int kg = l >> 4;
        bf16x8 af[4], bfr[4];
#pragma unroll
        for (int m = 0; m < 4; ++m) {
            int row = m * 16 + (l & 15);
            af[m] = *(const bf16x8*)(Ab + row * 64 + ((kg ^ (row & 3)) * 16));
        }
#pragma unroll
        for (int n = 0; n < 4; ++n) {
            int col = wn0 + n * 16 + (l & 15);
            bfr[n] = *(const bf16x8*)(Bb + col * 64 + ((kg ^ (col & 3)) * 16));
        }
#pragma unroll
        for (int m = 0; m < 4; ++m)
#pragma unroll
            for (int n = 0; n < 4; ++n)
                acc[m][n] = __builtin_amdgcn_mfma_f32_16x16x32_bf16(
                    af[m], bfr[n], acc[m][n], 0, 0, 0);
        __syncthreads();   // drains vmcnt: stage(t+1) landed; buf reads done
    }

    // epilogue: 2 chunks of 32 rows through LDS, fast-math LSTM, bf16 h store
    float* gbuf = (float*)smem;
#pragma unroll
    for (int mm = 0; mm < 2; ++mm) {
#pragma unroll
        for (int mo = 0; mo < 2; ++mo) {
#pragma unroll
            for (int n = 0; n < 4; ++n)
#pragma unroll
                for (int r = 0; r < 4; ++r)
                    gbuf[(mo * 16 + (l >> 4) * 4 + r) * 516 + wn0 + n * 16 + (l & 15)] =
                        acc[mm * 2 + mo][n][r];
        }
        __syncthreads();
#pragma unroll
        for (int i = 0; i < 8; ++i) {
            int c = t + 512 * i;            // 4096 cells = 32 rows x 128 dims
            int row = c >> 7, dim = c & 127;
            int u = u0 + mm * 32 + row;
            if (u < U_CNT) {
                float4 gv = *(const float4*)&gbuf[row * 516 + dim * 4];
                float4 bs = *(const float4*)&bsum_p[dim * 4];
                float I = gv.x + bs.x, F = gv.y + bs.y, G = gv.z + bs.z, O = gv.w + bs.w;
                float cxv = cx[(size_t)u * 128 + dim];
                float cn = sig_fast(F) * cxv + sig_fast(I) * tanh_fast(G);
                hout[(size_t)u * 256 + dim] = f2bf(sig_fast(O) * tanh_fast(cn));
            }
        }
        __syncthreads();
    }
}

// half-wave (32 lanes) per k; lane lid holds dims 4*lid..4*lid+3 (bf16 h + bf16 news)
__global__ void k_score(const unsigned short* __restrict__ hbf,
                        const unsigned short* __restrict__ nbf,
                        const int* __restrict__ ns_idx, const int* __restrict__ usi,
                        float* __restrict__ out) {
    int gh  = (blockIdx.x * 256 + threadIdx.x) >> 5;
    int lid = threadIdx.x & 31;
    if (gh >= K_CNT) return;
    int u = usi[gh];
    ushort4 hv = *(const ushort4*)&hbf[(size_t)u * 256 + lid * 4];
    float h0 = bf2f(hv.x), h1 = bf2f(hv.y), h2 = bf2f(hv.z), h3 = bf2f(hv.w);
    const int* np = ns_idx + gh * 9;
    float val = 0.f;
#pragma unroll
    for (int j = 0; j < 9; ++j) {
        int n = np[j];
        ushort4 nv = *(const ushort4*)&nbf[(size_t)n * 128 + lid * 4];
        float p = h0 * bf2f(nv.x) + h1 * bf2f(nv.y) + h2 * bf2f(nv.z) + h3 * bf2f(nv.w);
#pragma unroll
        for (int off = 16; off; off >>= 1) p += __shfl_xor(p, off, 64);  // stays in 32-group
        if (lid == j) val = p;
    }
    if (lid < 9) out[(size_t)gh * 9 + lid] = val;
}

extern "C" void kernel_launch(void* const* d_in, const int* in_sizes, int n_in,
                              void* d_out, int out_size, void* d_ws, size_t ws_size,
                              hipStream_t stream) {
    const float* user_emb = (const float*)d_in[0];
    const float* news_emb = (const float*)d_in[1];
    const float* cat_emb  = (const float*)d_in[2];
    const float* cx       = (const float*)d_in[3];
    const float* W_ih     = (const float*)d_in[4];
    const float* W_hh     = (const float*)d_in[5];
    const float* b_ih     = (const float*)d_in[6];
    const float* b_hh     = (const float*)d_in[7];
    const int* edge_src   = (const int*)d_in[8];
    const int* edge_dst   = (const int*)d_in[9];
    const int* edge_cat   = (const int*)d_in[10];
    const int* ns_idx     = (const int*)d_in[11];
    const int* usi        = (const int*)d_in[12];
    float* out = (float*)d_out;

    char* ws = (char*)d_ws;
    int*            cnt    = (int*)(ws + OFF_CNT);
    unsigned short* Bpt    = (unsigned short*)(ws + OFF_BPT);
    float*          bsum_p = (float*)(ws + OFF_BSUM);
    unsigned short* nbf    = (unsigned short*)(ws + OFF_NBF);
    int*            bucket = (int*)(ws + OFF_BUCKET);
    unsigned short* Abf    = (unsigned short*)(ws + OFF_ABF);
    unsigned short* hbf    = (unsigned short*)(ws + OFF_ABF);  // row-aligned alias

    k_zero<<<(U_CNT + 255) / 256, 256, 0, stream>>>(cnt);
    k_prep<<<512, 256, 0, stream>>>(W_ih, W_hh, b_ih, b_hh, Bpt, bsum_p);
    k_nbf<<<6250, 256, 0, stream>>>(news_emb, nbf);
    k_bucket<<<(E_CNT + 255) / 256, 256, 0, stream>>>(edge_dst, edge_src, edge_cat, cnt, bucket);
    k_agg<<<25000, 256, 0, stream>>>(user_emb, nbf, cat_emb, cnt, bucket, Abf);
    k_gemm_lstm<<<NBLK, 512, 0, stream>>>(Abf, Bpt, bsum_p, cx, hbf);
    k_score<<<(K_CNT * 32 + 255) / 256, 256, 0, stream>>>(hbf, nbf, ns_idx, usi, out);
}

// Round 9
// 401.619 us; speedup vs baseline: 2.3105x; 1.0638x over previous
//
#include <hip/hip_runtime.h>
#include <math.h>

#define U_CNT 100000
#define N_CNT 50000
#define C_CNT 20
#define D_DIM 128
#define E_CNT 1000000
#define K_CNT 50000
#define NS_CNT 9
#define CAP 64

#define BM 64
#define NB2 3126             // 1563 M-blocks x 2 N-blocks

// ---------------- workspace layout (bytes) ----------------
#define OFF_CNT    0                    // U*4 = 400000
#define OFF_BPT    400384               // 512*256*2 = 262144 (bf16 B, permuted+transposed+swizzled)
#define OFF_BSUM   662528               // 512*4 = 2048
#define OFF_NBF    665600               // 50000*128*2 = 12800000 (bf16 news)
#define OFF_BUCKET 13465600             // U*CAP*4 = 25600000 (packed src|cat<<16); hbf reuses this
#define OFF_ABF    39065664             // 100032*256*2 = 51216384
// end ~90.3MB.  hbf (dense [u][128] bf16, 25.6MB) aliases BUCKET (dead after k_agg).

typedef __attribute__((ext_vector_type(8))) short bf16x8;
typedef __attribute__((ext_vector_type(4))) float f32x4;

__device__ __forceinline__ unsigned short f2bf(float f) {
    unsigned u = __builtin_bit_cast(unsigned, f);
    u = (u + 0x7FFF + ((u >> 16) & 1)) >> 16;   // RNE; inputs finite
    return (unsigned short)u;
}
__device__ __forceinline__ float bf2f(unsigned short b) {
    return __builtin_bit_cast(float, (unsigned)b << 16);
}

// fast sigmoid/tanh: v_exp_f32 + v_rcp_f32 instead of libm exp/tanh + IEEE divides
__device__ __forceinline__ float sig_fast(float x) {
    float t = __builtin_amdgcn_exp2f(x * -1.44269504f);
    return __builtin_amdgcn_rcpf(1.f + t);
}
__device__ __forceinline__ float tanh_fast(float x) {
    x = fminf(fmaxf(x, -15.f), 15.f);
    float t = __builtin_amdgcn_exp2f(x * 2.88539008f);
    return (t - 1.f) * __builtin_amdgcn_rcpf(t + 1.f);
}

__device__ __forceinline__ void gload16(const void* g, void* l) {
    __builtin_amdgcn_global_load_lds(
        (const __attribute__((address_space(1))) unsigned int*)g,
        (__attribute__((address_space(3))) unsigned int*)l, 16, 0, 0);
}

__global__ void k_zero(int* __restrict__ cnt) {
    int i = blockIdx.x * 256 + threadIdx.x;
    if (i < U_CNT) cnt[i] = 0;
}

// Bpt[col][kp]: col=j'=d*4+g; element (col,k) at kp=(k>>6)*64+(((k>>3)&7)^(col&7))*8+(k&7)
__global__ void k_prep(const float* __restrict__ Wih, const float* __restrict__ Whh,
                       const float* __restrict__ bih, const float* __restrict__ bhh,
                       unsigned short* __restrict__ Bpt, float* __restrict__ bsum_p) {
    int idx = blockIdx.x * 256 + threadIdx.x;
    if (idx < 512) {
        int dim = idx >> 2, g = idx & 3;
        bsum_p[idx] = bih[g * 128 + dim] + bhh[g * 128 + dim];
    }
    if (idx >= 512 * 256) return;
    int col = idx >> 8, kp = idx & 255;
    int seg = kp >> 6, gst = (kp >> 3) & 7, e = kp & 7;
    int k = seg * 64 + (gst ^ (col & 7)) * 8 + e;
    int d = col >> 2, g = col & 3;
    int j = g * 128 + d;
    float v = (k < 128) ? Wih[j * 128 + k] : Whh[j * 128 + (k - 128)];
    Bpt[idx] = f2bf(v);
}

// news f32 -> bf16
__global__ void k_nbf(const float* __restrict__ news, unsigned short* __restrict__ nbf) {
    int i = blockIdx.x * 256 + threadIdx.x;
    if (i >= N_CNT * 32) return;
    float4 v = ((const float4*)news)[i];
    ushort4 o = {f2bf(v.x), f2bf(v.y), f2bf(v.z), f2bf(v.w)};
    ((ushort4*)nbf)[i] = o;
}

__global__ void k_bucket(const int* __restrict__ dst, const int* __restrict__ esrc,
                         const int* __restrict__ ecat, int* __restrict__ cnt,
                         int* __restrict__ bucket) {
    int e = blockIdx.x * 256 + threadIdx.x;
    if (e >= E_CNT) return;
    int d = dst[e];
    int slot = atomicAdd(&cnt[d], 1);
    if (slot < CAP) bucket[d * CAP + slot] = (esrc[e] & 0xFFFF) | (ecat[e] << 16);
}

// one wave per user, half-wave edge parallelism (unchanged; proven in round 6)
__global__ void k_agg(const float* __restrict__ user_emb,
                      const unsigned short* __restrict__ news_bf,
                      const float* __restrict__ cat_emb,
                      const int* __restrict__ cnt,
                      const int* __restrict__ bucket,
                      unsigned short* __restrict__ Abf) {
    int wid  = (blockIdx.x * blockDim.x + threadIdx.x) >> 6;
    int lane = threadIdx.x & 63;
    if (wid >= U_CNT) return;
    int deg = cnt[wid];
    if (deg > CAP) deg = CAP;
    int half = lane >> 5, lid = lane & 31;
    const int* bp = bucket + wid * CAP;
    float4 acc = {0.f, 0.f, 0.f, 0.f};
    int trips = (deg + 1) >> 1;
    int p = 0; float vmask = 0.f;
    if (trips > 0) {
        int e0 = half;
        p = bp[e0 < deg ? e0 : 0];
        vmask = (e0 < deg) ? 1.f : 0.f;
    }
    for (int t = 0; t < trips; ++t) {
        int en = 2 * (t + 1) + half;
        int pn = 0; float vn = 0.f;
        if (t + 1 < trips) {
            pn = bp[en < deg ? en : 0];
            vn = (en < deg) ? 1.f : 0.f;
        }
        int s = p & 0xFFFF;
        int c = p >> 16;
        ushort4 nv = *(const ushort4*)&news_bf[(size_t)s * 128 + lid * 4];
        float4  cv = *(const float4*)&cat_emb[c * 128 + lid * 4];
        acc.x += vmask * bf2f(nv.x) * cv.x;
        acc.y += vmask * bf2f(nv.y) * cv.y;
        acc.z += vmask * bf2f(nv.z) * cv.z;
        acc.w += vmask * bf2f(nv.w) * cv.w;
        p = pn; vmask = vn;
    }
    acc.x += __shfl_xor(acc.x, 32, 64);
    acc.y += __shfl_xor(acc.y, 32, 64);
    acc.z += __shfl_xor(acc.z, 32, 64);
    acc.w += __shfl_xor(acc.w, 32, 64);
    if (half == 0) {
        float inv = 1.0f / (float)(deg < 1 ? 1 : deg);
        float4 ue = *(const float4*)&user_emb[(size_t)wid * 128 + lid * 4];
        float4 xv = {ue.x + acc.x * inv, ue.y + acc.y * inv,
                     ue.z + acc.z * inv, ue.w + acc.w * inv};
        int seg = lid >> 4;
        int gr  = (lid >> 1) & 7;
        int eo  = (lid & 1) * 4;
        int pos = seg * 64 + ((gr ^ (wid & 7)) * 8) + eo;
        size_t base = (size_t)wid * 256;
        ushort4 xb = {f2bf(xv.x), f2bf(xv.y), f2bf(xv.z), f2bf(xv.w)};
        ushort4 ub = {f2bf(ue.x), f2bf(ue.y), f2bf(ue.z), f2bf(ue.w)};
        *(ushort4*)&Abf[base + pos] = xb;
        *(ushort4*)&Abf[base + 128 + pos] = ub;
    }
}

// MFMA GEMM, BM=64 x BN=256 (N-split 2: nb picks dims 64*nb..64*nb+63, all 4 gates),
// BK=64 (128B LDS rows, 8-slot swizzle -> conflict-free b128 reads, as in round 6),
// double-buffered: 2 x (A 8KB + B 32KB) = 80KB -> exactly 2 blocks/CU.
// 8 waves, wave w owns 32 cols. 4 K-steps. h written DENSE bf16 [u][128] into the
// dead bucket region (no Abf alias -> no cross-N-block race).
#define STAGE(S, BUF)                                                                    \
    {                                                                                    \
        char* Ab_ = smem + (BUF) * 8192;                                                 \
        char* Bb_ = smem + 16384 + (BUF) * 32768;                                        \
        _Pragma("unroll")                                                                \
        for (int ii = 0; ii < 5; ++ii) {                                                 \
            int inst = w * 5 + ii;                                                       \
            if (inst < 8) {                                                              \
                int row = inst * 8 + (l >> 3);                                           \
                gload16(Abf + (size_t)(u0 + row) * 256 + (S) * 64 + (l & 7) * 8,         \
                        Ab_ + inst * 1024 + l * 16);                                     \
            } else {                                                                     \
                int b = inst - 8;                                                        \
                int gcol = n0 + b * 8 + (l >> 3);                                        \
                gload16(Bpt + (size_t)gcol * 256 + (S) * 64 + (l & 7) * 8,               \
                        Bb_ + b * 1024 + l * 16);                                        \
            }                                                                            \
        }                                                                                \
    }

__global__ __launch_bounds__(512, 4) void k_gemm_lstm(
    const unsigned short* __restrict__ Abf, const unsigned short* __restrict__ Bpt,
    const float* __restrict__ bsum_p, const float* __restrict__ cx,
    unsigned short* __restrict__ hbf)    // dense bf16 [u][128] (bucket region)
{
    __shared__ __align__(16) char smem[81920];  // A dbuf 2x8KB @0, B dbuf 2x32KB @16384
    int t = threadIdx.x, l = t & 63, w = t >> 6;
    int mb = blockIdx.x >> 1, nb = blockIdx.x & 1;
    int u0 = mb * BM;
    int n0 = nb * 256;          // global col base (permuted j' space)
    int wn0 = w * 32;           // wave's local col base

    f32x4 acc[4][2];
#pragma unroll
    for (int m = 0; m < 4; ++m)
#pragma unroll
        for (int n = 0; n < 2; ++n) acc[m][n] = (f32x4){0.f, 0.f, 0.f, 0.f};

    STAGE(0, 0);
    asm volatile("s_waitcnt vmcnt(0)" ::: "memory");
    __syncthreads();

#pragma unroll
    for (int step = 0; step < 4; ++step) {
        int cur = step & 1;
        if (step < 3) STAGE(step + 1, cur ^ 1);   // prefetch next K-slice
        const char* Ab = smem + cur * 8192;
        const char* Bb = smem + 16384 + cur * 32768;
#pragma unroll
        for (int kf = 0; kf < 2; ++kf) {
            int swz = ((kf * 4 + (l >> 4)) ^ (l & 7)) * 16;
            bf16x8 af[4], bfr[2];
#pragma unroll
            for (int m = 0; m < 4; ++m)
                af[m] = *(const bf16x8*)(Ab + (m * 16 + (l & 15)) * 128 + swz);
#pragma unroll
            for (int n = 0; n < 2; ++n)
                bfr[n] = *(const bf16x8*)(Bb + (wn0 + n * 16 + (l & 15)) * 128 + swz);
#pragma unroll
            for (int m = 0; m < 4; ++m)
#pragma unroll
                for (int n = 0; n < 2; ++n)
                    acc[m][n] = __builtin_amdgcn_mfma_f32_16x16x32_bf16(
                        af[m], bfr[n], acc[m][n], 0, 0, 0);
        }
        __syncthreads();   // drains vmcnt: prefetch landed; buffer reads done
    }

    // epilogue: gates tile 64 users x 64 dims (x4 gates) through LDS, fast-math LSTM
    float* gbuf = (float*)smem;    // [64][260]
#pragma unroll
    for (int m = 0; m < 4; ++m)
#pragma unroll
        for (int n = 0; n < 2; ++n)
#pragma unroll
            for (int r = 0; r < 4; ++r)
                gbuf[(m * 16 + (l >> 4) * 4 + r) * 260 + wn0 + n * 16 + (l & 15)] =
                    acc[m][n][r];
    __syncthreads();
#pragma unroll
    for (int i = 0; i < 8; ++i) {
        int c = t + 512 * i;            // 4096 cells = 64 rows x 64 dims
        int row = c >> 6, dloc = c & 63;
        int u = u0 + row;
        if (u < U_CNT) {
            int gdim = nb * 64 + dloc;
            float4 gv = *(const float4*)&gbuf[row * 260 + dloc * 4];
            float4 bs = *(const float4*)&bsum_p[gdim * 4];
            float I = gv.x + bs.x, F = gv.y + bs.y, G = gv.z + bs.z, O = gv.w + bs.w;
            float cxv = cx[(size_t)u * 128 + gdim];
            float cn = sig_fast(F) * cxv + sig_fast(I) * tanh_fast(G);
            hbf[(size_t)u * 128 + gdim] = f2bf(sig_fast(O) * tanh_fast(cn));
        }
    }
}

// half-wave (32 lanes) per k; lane lid holds dims 4*lid..4*lid+3 (dense bf16 h + bf16 news)
__global__ void k_score(const unsigned short* __restrict__ hbf,
                        const unsigned short* __restrict__ nbf,
                        const int* __restrict__ ns_idx, const int* __restrict__ usi,
                        float* __restrict__ out) {
    int gh  = (blockIdx.x * 256 + threadIdx.x) >> 5;
    int lid = threadIdx.x & 31;
    if (gh >= K_CNT) return;
    int u = usi[gh];
    ushort4 hv = *(const ushort4*)&hbf[(size_t)u * 128 + lid * 4];
    float h0 = bf2f(hv.x), h1 = bf2f(hv.y), h2 = bf2f(hv.z), h3 = bf2f(hv.w);
    const int* np = ns_idx + gh * 9;
    float val = 0.f;
#pragma unroll
    for (int j = 0; j < 9; ++j) {
        int n = np[j];
        ushort4 nv = *(const ushort4*)&nbf[(size_t)n * 128 + lid * 4];
        float p = h0 * bf2f(nv.x) + h1 * bf2f(nv.y) + h2 * bf2f(nv.z) + h3 * bf2f(nv.w);
#pragma unroll
        for (int off = 16; off; off >>= 1) p += __shfl_xor(p, off, 64);
        if (lid == j) val = p;
    }
    if (lid < 9) out[(size_t)gh * 9 + lid] = val;
}

extern "C" void kernel_launch(void* const* d_in, const int* in_sizes, int n_in,
                              void* d_out, int out_size, void* d_ws, size_t ws_size,
                              hipStream_t stream) {
    const float* user_emb = (const float*)d_in[0];
    const float* news_emb = (const float*)d_in[1];
    const float* cat_emb  = (const float*)d_in[2];
    const float* cx       = (const float*)d_in[3];
    const float* W_ih     = (const float*)d_in[4];
    const float* W_hh     = (const float*)d_in[5];
    const float* b_ih     = (const float*)d_in[6];
    const float* b_hh     = (const float*)d_in[7];
    const int* edge_src   = (const int*)d_in[8];
    const int* edge_dst   = (const int*)d_in[9];
    const int* edge_cat   = (const int*)d_in[10];
    const int* ns_idx     = (const int*)d_in[11];
    const int* usi        = (const int*)d_in[12];
    float* out = (float*)d_out;

    char* ws = (char*)d_ws;
    int*            cnt    = (int*)(ws + OFF_CNT);
    unsigned short* Bpt    = (unsigned short*)(ws + OFF_BPT);
    float*          bsum_p = (float*)(ws + OFF_BSUM);
    unsigned short* nbf    = (unsigned short*)(ws + OFF_NBF);
    int*            bucket = (int*)(ws + OFF_BUCKET);
    unsigned short* Abf    = (unsigned short*)(ws + OFF_ABF);
    unsigned short* hbf    = (unsigned short*)(ws + OFF_BUCKET);  // reuse (dead after k_agg)

    k_zero<<<(U_CNT + 255) / 256, 256, 0, stream>>>(cnt);
    k_prep<<<512, 256, 0, stream>>>(W_ih, W_hh, b_ih, b_hh, Bpt, bsum_p);
    k_nbf<<<6250, 256, 0, stream>>>(news_emb, nbf);
    k_bucket<<<(E_CNT + 255) / 256, 256, 0, stream>>>(edge_dst, edge_src, edge_cat, cnt, bucket);
    k_agg<<<25000, 256, 0, stream>>>(user_emb, nbf, cat_emb, cnt, bucket, Abf);
    k_gemm_lstm<<<NB2, 512, 0, stream>>>(Abf, Bpt, bsum_p, cx, hbf);
    k_score<<<(K_CNT * 32 + 255) / 256, 256, 0, stream>>>(hbf, nbf, ns_idx, usi, out);
}

// Round 10
// 377.737 us; speedup vs baseline: 2.4566x; 1.0632x over previous
//
#include <hip/hip_runtime.h>
#include <math.h>

#define U_CNT 100000
#define N_CNT 50000
#define C_CNT 20
#define D_DIM 128
#define E_CNT 1000000
#define K_CNT 50000
#define NS_CNT 9
#define CAP 64

#define BM 64
#define NB2 3126             // 1563 M-blocks x 2 N-blocks

// ---------------- workspace layout (bytes) ----------------
#define OFF_CNT    0                    // U*4 = 400000
#define OFF_BPT    400384               // 512*256*2 = 262144 (bf16 B, permuted+transposed+swizzled)
#define OFF_BSUM   662528               // 512*4 = 2048
#define OFF_NBF    665600               // 50000*128*2 = 12800000 (bf16 news)
#define OFF_BUCKET 13465600             // U*CAP*4 = 25600000 (packed src|cat<<16); hbf reuses this
#define OFF_ABF    39065664             // 100032*256*2 = 51216384
// end ~90.3MB.  hbf (dense [u][128] bf16, 25.6MB) aliases BUCKET (dead after k_agg).

typedef __attribute__((ext_vector_type(8))) short bf16x8;
typedef __attribute__((ext_vector_type(4))) float f32x4;

__device__ __forceinline__ unsigned short f2bf(float f) {
    unsigned u = __builtin_bit_cast(unsigned, f);
    u = (u + 0x7FFF + ((u >> 16) & 1)) >> 16;   // RNE; inputs finite
    return (unsigned short)u;
}
__device__ __forceinline__ float bf2f(unsigned short b) {
    return __builtin_bit_cast(float, (unsigned)b << 16);
}

// fast sigmoid/tanh: v_exp_f32 + v_rcp_f32 instead of libm exp/tanh + IEEE divides
__device__ __forceinline__ float sig_fast(float x) {
    float t = __builtin_amdgcn_exp2f(x * -1.44269504f);
    return __builtin_amdgcn_rcpf(1.f + t);
}
__device__ __forceinline__ float tanh_fast(float x) {
    x = fminf(fmaxf(x, -15.f), 15.f);
    float t = __builtin_amdgcn_exp2f(x * 2.88539008f);
    return (t - 1.f) * __builtin_amdgcn_rcpf(t + 1.f);
}

__device__ __forceinline__ void gload16(const void* g, void* l) {
    __builtin_amdgcn_global_load_lds(
        (const __attribute__((address_space(1))) unsigned int*)g,
        (__attribute__((address_space(3))) unsigned int*)l, 16, 0, 0);
}

__global__ void k_zero(int* __restrict__ cnt) {
    int i = blockIdx.x * 256 + threadIdx.x;
    if (i < U_CNT) cnt[i] = 0;
}

// Bpt[col][kp]: col=j'=d*4+g; element (col,k) at kp=(k>>6)*64+(((k>>3)&7)^(col&7))*8+(k&7)
__global__ void k_prep(const float* __restrict__ Wih, const float* __restrict__ Whh,
                       const float* __restrict__ bih, const float* __restrict__ bhh,
                       unsigned short* __restrict__ Bpt, float* __restrict__ bsum_p) {
    int idx = blockIdx.x * 256 + threadIdx.x;
    if (idx < 512) {
        int dim = idx >> 2, g = idx & 3;
        bsum_p[idx] = bih[g * 128 + dim] + bhh[g * 128 + dim];
    }
    if (idx >= 512 * 256) return;
    int col = idx >> 8, kp = idx & 255;
    int seg = kp >> 6, gst = (kp >> 3) & 7, e = kp & 7;
    int k = seg * 64 + (gst ^ (col & 7)) * 8 + e;
    int d = col >> 2, g = col & 3;
    int j = g * 128 + d;
    float v = (k < 128) ? Wih[j * 128 + k] : Whh[j * 128 + (k - 128)];
    Bpt[idx] = f2bf(v);
}

// news f32 -> bf16
__global__ void k_nbf(const float* __restrict__ news, unsigned short* __restrict__ nbf) {
    int i = blockIdx.x * 256 + threadIdx.x;
    if (i >= N_CNT * 32) return;
    float4 v = ((const float4*)news)[i];
    ushort4 o = {f2bf(v.x), f2bf(v.y), f2bf(v.z), f2bf(v.w)};
    ((ushort4*)nbf)[i] = o;
}

__global__ void k_bucket(const int* __restrict__ dst, const int* __restrict__ esrc,
                         const int* __restrict__ ecat, int* __restrict__ cnt,
                         int* __restrict__ bucket) {
    int e = blockIdx.x * 256 + threadIdx.x;
    if (e >= E_CNT) return;
    int d = dst[e];
    int slot = atomicAdd(&cnt[d], 1);
    if (slot < CAP) bucket[d * CAP + slot] = (esrc[e] & 0xFFFF) | (ecat[e] << 16);
}

// one wave per user, QUARTER-wave edge parallelism: 4 edge-groups x 16 lanes,
// lane lid holds dims 8*lid..8*lid+7 (bf16x8 news gather = 16B/lane, 4 edges in
// flight -> 2x MLP vs round 9). cat stays f32 (10KB table, L1-hot).
__global__ void k_agg(const float* __restrict__ user_emb,
                      const unsigned short* __restrict__ news_bf,
                      const float* __restrict__ cat_emb,
                      const int* __restrict__ cnt,
                      const int* __restrict__ bucket,
                      unsigned short* __restrict__ Abf) {
    int wid  = (blockIdx.x * blockDim.x + threadIdx.x) >> 6;
    int lane = threadIdx.x & 63;
    if (wid >= U_CNT) return;
    int deg = cnt[wid];
    if (deg > CAP) deg = CAP;
    int grp = lane >> 4, lid = lane & 15;
    const int* bp = bucket + wid * CAP;
    float acc[8] = {0.f, 0.f, 0.f, 0.f, 0.f, 0.f, 0.f, 0.f};
    int trips = (deg + 3) >> 2;
    int p = 0; float vmask = 0.f;
    if (trips > 0) {
        int e0 = grp;
        p = bp[e0 < deg ? e0 : 0];
        vmask = (e0 < deg) ? 1.f : 0.f;
    }
    for (int t = 0; t < trips; ++t) {
        int en = 4 * (t + 1) + grp;
        int pn = 0; float vn = 0.f;
        if (t + 1 < trips) {
            pn = bp[en < deg ? en : 0];
            vn = (en < deg) ? 1.f : 0.f;
        }
        int s = p & 0xFFFF;
        int c = p >> 16;
        bf16x8 nv = *(const bf16x8*)&news_bf[(size_t)s * 128 + lid * 8];
        const float* cp = &cat_emb[c * 128 + lid * 8];
        float4 cv0 = *(const float4*)cp;
        float4 cv1 = *(const float4*)(cp + 4);
        acc[0] += vmask * bf2f((unsigned short)nv[0]) * cv0.x;
        acc[1] += vmask * bf2f((unsigned short)nv[1]) * cv0.y;
        acc[2] += vmask * bf2f((unsigned short)nv[2]) * cv0.z;
        acc[3] += vmask * bf2f((unsigned short)nv[3]) * cv0.w;
        acc[4] += vmask * bf2f((unsigned short)nv[4]) * cv1.x;
        acc[5] += vmask * bf2f((unsigned short)nv[5]) * cv1.y;
        acc[6] += vmask * bf2f((unsigned short)nv[6]) * cv1.z;
        acc[7] += vmask * bf2f((unsigned short)nv[7]) * cv1.w;
        p = pn; vmask = vn;
    }
#pragma unroll
    for (int i = 0; i < 8; ++i) {
        acc[i] += __shfl_xor(acc[i], 16, 64);
        acc[i] += __shfl_xor(acc[i], 32, 64);
    }
    if (grp == 0) {
        float inv = 1.0f / (float)(deg < 1 ? 1 : deg);
        const float* up = &user_emb[(size_t)wid * 128 + lid * 8];
        float4 ue0 = *(const float4*)up;
        float4 ue1 = *(const float4*)(up + 4);
        bf16x8 xb, ub;
        xb[0] = (short)f2bf(ue0.x + acc[0] * inv);
        xb[1] = (short)f2bf(ue0.y + acc[1] * inv);
        xb[2] = (short)f2bf(ue0.z + acc[2] * inv);
        xb[3] = (short)f2bf(ue0.w + acc[3] * inv);
        xb[4] = (short)f2bf(ue1.x + acc[4] * inv);
        xb[5] = (short)f2bf(ue1.y + acc[5] * inv);
        xb[6] = (short)f2bf(ue1.z + acc[6] * inv);
        xb[7] = (short)f2bf(ue1.w + acc[7] * inv);
        ub[0] = (short)f2bf(ue0.x); ub[1] = (short)f2bf(ue0.y);
        ub[2] = (short)f2bf(ue0.z); ub[3] = (short)f2bf(ue0.w);
        ub[4] = (short)f2bf(ue1.x); ub[5] = (short)f2bf(ue1.y);
        ub[6] = (short)f2bf(ue1.z); ub[7] = (short)f2bf(ue1.w);
        // d=8*lid..8*lid+7: kp = (lid>>3)*64 + ((lid&7)^(wid&7))*8 + (0..7)
        int pos = (lid >> 3) * 64 + (((lid & 7) ^ (wid & 7)) * 8);
        size_t base = (size_t)wid * 256;
        *(bf16x8*)&Abf[base + pos] = xb;
        *(bf16x8*)&Abf[base + 128 + pos] = ub;
    }
}

// MFMA GEMM, BM=64 x BN=256, BK=64, double-buffered (unchanged from round 9)
#define STAGE(S, BUF)                                                                    \
    {                                                                                    \
        char* Ab_ = smem + (BUF) * 8192;                                                 \
        char* Bb_ = smem + 16384 + (BUF) * 32768;                                        \
        _Pragma("unroll")                                                                \
        for (int ii = 0; ii < 5; ++ii) {                                                 \
            int inst = w * 5 + ii;                                                       \
            if (inst < 8) {                                                              \
                int row = inst * 8 + (l >> 3);                                           \
                gload16(Abf + (size_t)(u0 + row) * 256 + (S) * 64 + (l & 7) * 8,         \
                        Ab_ + inst * 1024 + l * 16);                                     \
            } else {                                                                     \
                int b = inst - 8;                                                        \
                int gcol = n0 + b * 8 + (l >> 3);                                        \
                gload16(Bpt + (size_t)gcol * 256 + (S) * 64 + (l & 7) * 8,               \
                        Bb_ + b * 1024 + l * 16);                                        \
            }                                                                            \
        }                                                                                \
    }

__global__ __launch_bounds__(512, 4) void k_gemm_lstm(
    const unsigned short* __restrict__ Abf, const unsigned short* __restrict__ Bpt,
    const float* __restrict__ bsum_p, const float* __restrict__ cx,
    unsigned short* __restrict__ hbf)    // dense bf16 [u][128] (bucket region)
{
    __shared__ __align__(16) char smem[81920];  // A dbuf 2x8KB @0, B dbuf 2x32KB @16384
    int t = threadIdx.x, l = t & 63, w = t >> 6;
    int mb = blockIdx.x >> 1, nb = blockIdx.x & 1;
    int u0 = mb * BM;
    int n0 = nb * 256;          // global col base (permuted j' space)
    int wn0 = w * 32;           // wave's local col base

    f32x4 acc[4][2];
#pragma unroll
    for (int m = 0; m < 4; ++m)
#pragma unroll
        for (int n = 0; n < 2; ++n) acc[m][n] = (f32x4){0.f, 0.f, 0.f, 0.f};

    STAGE(0, 0);
    asm volatile("s_waitcnt vmcnt(0)" ::: "memory");
    __syncthreads();

#pragma unroll
    for (int step = 0; step < 4; ++step) {
        int cur = step & 1;
        if (step < 3) STAGE(step + 1, cur ^ 1);   // prefetch next K-slice
        const char* Ab = smem + cur * 8192;
        const char* Bb = smem + 16384 + cur * 32768;
#pragma unroll
        for (int kf = 0; kf < 2; ++kf) {
            int swz = ((kf * 4 + (l >> 4)) ^ (l & 7)) * 16;
            bf16x8 af[4], bfr[2];
#pragma unroll
            for (int m = 0; m < 4; ++m)
                af[m] = *(const bf16x8*)(Ab + (m * 16 + (l & 15)) * 128 + swz);
#pragma unroll
            for (int n = 0; n < 2; ++n)
                bfr[n] = *(const bf16x8*)(Bb + (wn0 + n * 16 + (l & 15)) * 128 + swz);
#pragma unroll
            for (int m = 0; m < 4; ++m)
#pragma unroll
                for (int n = 0; n < 2; ++n)
                    acc[m][n] = __builtin_amdgcn_mfma_f32_16x16x32_bf16(
                        af[m], bfr[n], acc[m][n], 0, 0, 0);
        }
        __syncthreads();   // drains vmcnt: prefetch landed; buffer reads done
    }

    // epilogue: gates tile 64 users x 64 dims (x4 gates) through LDS, fast-math LSTM
    float* gbuf = (float*)smem;    // [64][260]
#pragma unroll
    for (int m = 0; m < 4; ++m)
#pragma unroll
        for (int n = 0; n < 2; ++n)
#pragma unroll
            for (int r = 0; r < 4; ++r)
                gbuf[(m * 16 + (l >> 4) * 4 + r) * 260 + wn0 + n * 16 + (l & 15)] =
                    acc[m][n][r];
    __syncthreads();
#pragma unroll
    for (int i = 0; i < 8; ++i) {
        int c = t + 512 * i;            // 4096 cells = 64 rows x 64 dims
        int row = c >> 6, dloc = c & 63;
        int u = u0 + row;
        if (u < U_CNT) {
            int gdim = nb * 64 + dloc;
            float4 gv = *(const float4*)&gbuf[row * 260 + dloc * 4];
            float4 bs = *(const float4*)&bsum_p[gdim * 4];
            float I = gv.x + bs.x, F = gv.y + bs.y, G = gv.z + bs.z, O = gv.w + bs.w;
            float cxv = cx[(size_t)u * 128 + gdim];
            float cn = sig_fast(F) * cxv + sig_fast(I) * tanh_fast(G);
            hbf[(size_t)u * 128 + gdim] = f2bf(sig_fast(O) * tanh_fast(cn));
        }
    }
}

// QUARTER-wave (16 lanes) per k; lane lid holds dims 8*lid..8*lid+7 -> 4 k's in
// flight per wave (2x group MLP vs round 9); 4-step shfl reduce.
__global__ void k_score(const unsigned short* __restrict__ hbf,
                        const unsigned short* __restrict__ nbf,
                        const int* __restrict__ ns_idx, const int* __restrict__ usi,
                        float* __restrict__ out) {
    int gh  = (blockIdx.x * 256 + threadIdx.x) >> 4;
    int lid = threadIdx.x & 15;
    if (gh >= K_CNT) return;
    int u = usi[gh];
    bf16x8 hv = *(const bf16x8*)&hbf[(size_t)u * 128 + lid * 8];
    float h0 = bf2f((unsigned short)hv[0]), h1 = bf2f((unsigned short)hv[1]);
    float h2 = bf2f((unsigned short)hv[2]), h3 = bf2f((unsigned short)hv[3]);
    float h4 = bf2f((unsigned short)hv[4]), h5 = bf2f((unsigned short)hv[5]);
    float h6 = bf2f((unsigned short)hv[6]), h7 = bf2f((unsigned short)hv[7]);
    const int* np = ns_idx + gh * 9;
    float val = 0.f;
#pragma unroll
    for (int j = 0; j < 9; ++j) {
        int n = np[j];
        bf16x8 nv = *(const bf16x8*)&nbf[(size_t)n * 128 + lid * 8];
        float p = h0 * bf2f((unsigned short)nv[0]) + h1 * bf2f((unsigned short)nv[1])
                + h2 * bf2f((unsigned short)nv[2]) + h3 * bf2f((unsigned short)nv[3])
                + h4 * bf2f((unsigned short)nv[4]) + h5 * bf2f((unsigned short)nv[5])
                + h6 * bf2f((unsigned short)nv[6]) + h7 * bf2f((unsigned short)nv[7]);
#pragma unroll
        for (int off = 8; off; off >>= 1) p += __shfl_xor(p, off, 64);  // within 16-group
        if (lid == j) val = p;
    }
    if (lid < 9) out[(size_t)gh * 9 + lid] = val;
}

extern "C" void kernel_launch(void* const* d_in, const int* in_sizes, int n_in,
                              void* d_out, int out_size, void* d_ws, size_t ws_size,
                              hipStream_t stream) {
    const float* user_emb = (const float*)d_in[0];
    const float* news_emb = (const float*)d_in[1];
    const float* cat_emb  = (const float*)d_in[2];
    const float* cx       = (const float*)d_in[3];
    const float* W_ih     = (const float*)d_in[4];
    const float* W_hh     = (const float*)d_in[5];
    const float* b_ih     = (const float*)d_in[6];
    const float* b_hh     = (const float*)d_in[7];
    const int* edge_src   = (const int*)d_in[8];
    const int* edge_dst   = (const int*)d_in[9];
    const int* edge_cat   = (const int*)d_in[10];
    const int* ns_idx     = (const int*)d_in[11];
    const int* usi        = (const int*)d_in[12];
    float* out = (float*)d_out;

    char* ws = (char*)d_ws;
    int*            cnt    = (int*)(ws + OFF_CNT);
    unsigned short* Bpt    = (unsigned short*)(ws + OFF_BPT);
    float*          bsum_p = (float*)(ws + OFF_BSUM);
    unsigned short* nbf    = (unsigned short*)(ws + OFF_NBF);
    int*            bucket = (int*)(ws + OFF_BUCKET);
    unsigned short* Abf    = (unsigned short*)(ws + OFF_ABF);
    unsigned short* hbf    = (unsigned short*)(ws + OFF_BUCKET);  // reuse (dead after k_agg)

    k_zero<<<(U_CNT + 255) / 256, 256, 0, stream>>>(cnt);
    k_prep<<<512, 256, 0, stream>>>(W_ih, W_hh, b_ih, b_hh, Bpt, bsum_p);
    k_nbf<<<6250, 256, 0, stream>>>(news_emb, nbf);
    k_bucket<<<(E_CNT + 255) / 256, 256, 0, stream>>>(edge_dst, edge_src, edge_cat, cnt, bucket);
    k_agg<<<25000, 256, 0, stream>>>(user_emb, nbf, cat_emb, cnt, bucket, Abf);
    k_gemm_lstm<<<NB2, 512, 0, stream>>>(Abf, Bpt, bsum_p, cx, hbf);
    k_score<<<(K_CNT * 16 + 255) / 256, 256, 0, stream>>>(hbf, nbf, ns_idx, usi, out);
}